// Round 2
// baseline (1428.733 us; speedup 1.0000x reference)
//
#include <hip/hip_runtime.h>
#include <hip/hip_bf16.h>
#include <stdint.h>

// Problem: B=4, T=2048, D=2048, H=16, HD=128.  out = Attn(xWq, xWk, xWv) Wo
#define TT   2048
#define DD   2048
#define NH   16
#define NB   4
#define HDIM 128
#define MSZ  (NB * TT)      // 8192 rows for the token-major GEMMs
#define NQKV (3 * DD)       // 6144 fused QKV output columns

typedef __attribute__((ext_vector_type(8))) __bf16 bf16x8;
typedef __attribute__((ext_vector_type(4))) float  f32x4;

typedef __attribute__((address_space(3))) void       lds_void;
typedef const __attribute__((address_space(1))) void g_void;

__device__ inline unsigned short f2bf(float f) {
  union { float f; unsigned u; } v; v.f = f;
  unsigned r = v.u + 0x7fffu + ((v.u >> 16) & 1u);  // round-to-nearest-even
  return (unsigned short)(r >> 16);
}

__device__ inline void gload16(const void* g, void* l) {
  __builtin_amdgcn_global_load_lds((g_void*)g, (lds_void*)l, 16, 0, 0);
}

__device__ inline f32x4 mfma16(bf16x8 a, bf16x8 b, f32x4 c) {
  return __builtin_amdgcn_mfma_f32_16x16x32_bf16(a, b, c, 0, 0, 0);
}

// ---------------------------------------------------------------- cvt x->bf16
__global__ __launch_bounds__(256) void cvtx(const float* __restrict__ x,
                                            unsigned short* __restrict__ xb) {
  const int n4 = MSZ * DD / 4;
  for (int i = blockIdx.x * blockDim.x + threadIdx.x; i < n4;
       i += gridDim.x * blockDim.x) {
    float4 v = ((const float4*)x)[i];
    uint2 u;
    u.x = (unsigned)f2bf(v.x) | ((unsigned)f2bf(v.y) << 16);
    u.y = (unsigned)f2bf(v.z) | ((unsigned)f2bf(v.w) << 16);
    *(uint2*)&xb[(size_t)i * 4] = u;
  }
}

// ------------------------------------------- W (K,N) f32 -> Wt (N,K) bf16
__global__ __launch_bounds__(256) void transW(const float* __restrict__ Wq,
                                              const float* __restrict__ Wk,
                                              const float* __restrict__ Wv,
                                              const float* __restrict__ Wo,
                                              unsigned short* __restrict__ Wtq,
                                              unsigned short* __restrict__ Wto) {
  __shared__ float tl[32][33];
  const int z = blockIdx.z;
  const float* W = (z == 0) ? Wq : (z == 1) ? Wk : (z == 2) ? Wv : Wo;
  unsigned short* outp = (z < 3) ? (Wtq + (size_t)z * DD * DD) : Wto;
  const int c = threadIdx.x & 31, r8 = threadIdx.x >> 5;
  const int k0 = blockIdx.y * 32, n0 = blockIdx.x * 32;
#pragma unroll
  for (int i = 0; i < 4; ++i)
    tl[r8 + 8 * i][c] = W[(size_t)(k0 + r8 + 8 * i) * DD + n0 + c];
  __syncthreads();
#pragma unroll
  for (int i = 0; i < 4; ++i)
    outp[(size_t)(n0 + r8 + 8 * i) * DD + k0 + c] = f2bf(tl[c][r8 + 8 * i]);
}

// --------------------------------------------------------------- GEMM (B^T)
// C[M,N] = A[M,K] * Bt[N,K]^T, K = 2048, 128x128 tile, 4 waves of 64x64.
// EPI 0: fused-QKV epilogue (Q scaled, K normal, V transposed), bf16 out.
// EPI 1: plain f32 store to Cf (the final projection, writes d_out).
template <int EPI>
__global__ __launch_bounds__(256) void gemm_bt(
    const unsigned short* __restrict__ A, const unsigned short* __restrict__ Bt,
    unsigned short* __restrict__ Qb, unsigned short* __restrict__ Kb,
    unsigned short* __restrict__ Vt, float* __restrict__ Cf) {
  __shared__ __align__(16) unsigned short As[128 * 32];
  __shared__ __align__(16) unsigned short Bs[128 * 32];
  const int tid = threadIdx.x;
  const int m0 = blockIdx.y * 128;
  const int n0 = blockIdx.x * 128;
  const int lane = tid & 63;
  const int w = tid >> 6;
  const int wr = (w >> 1) * 64;
  const int wc = (w & 1) * 64;
  const int l15 = lane & 15;
  const int g = lane >> 4;

  const unsigned short* gA0 = A + (size_t)(m0 + (tid >> 2)) * DD + (tid & 3) * 8;
  const unsigned short* gA1 = gA0 + (size_t)64 * DD;
  const unsigned short* gB0 = Bt + (size_t)(n0 + (tid >> 2)) * DD + (tid & 3) * 8;
  const unsigned short* gB1 = gB0 + (size_t)64 * DD;
  unsigned short* lA0 = &As[tid * 8];
  unsigned short* lA1 = &As[(tid + 256) * 8];
  unsigned short* lB0 = &Bs[tid * 8];
  unsigned short* lB1 = &Bs[(tid + 256) * 8];

  f32x4 acc[4][4] = {};

  for (int ks = 0; ks < DD / 32; ++ks) {
    __syncthreads();  // prior iter's LDS reads complete
    gload16(gA0, lA0); gload16(gA1, lA1);
    gload16(gB0, lB0); gload16(gB1, lB1);
    gA0 += 32; gA1 += 32; gB0 += 32; gB1 += 32;
    __syncthreads();  // drains vmcnt -> tiles resident

    bf16x8 afr[4], bfr[4];
#pragma unroll
    for (int m = 0; m < 4; ++m)
      afr[m] = *(const bf16x8*)&As[(wr + m * 16 + l15) * 32 + g * 8];
#pragma unroll
    for (int n = 0; n < 4; ++n)
      bfr[n] = *(const bf16x8*)&Bs[(wc + n * 16 + l15) * 32 + g * 8];
#pragma unroll
    for (int m = 0; m < 4; ++m)
#pragma unroll
      for (int n = 0; n < 4; ++n)
        acc[m][n] = mfma16(afr[m], bfr[n], acc[m][n]);
  }

  // Epilogue. C frag: row = 4*g + r, col = l15 (m89-verified mapping).
  const float RSCALE = 0.08838834764831845f;  // 1/sqrt(HD)
#pragma unroll
  for (int m = 0; m < 4; ++m) {
#pragma unroll
    for (int n = 0; n < 4; ++n) {
      const int row0 = m0 + wr + m * 16 + 4 * g;
      const int col = n0 + wc + n * 16 + l15;
      if (EPI == 1) {
#pragma unroll
        for (int r = 0; r < 4; ++r)
          Cf[(size_t)(row0 + r) * DD + col] = acc[m][n][r];
      } else {
        const int mat = n0 >> 11;             // uniform per block
        const int h = (n0 & 2047) >> 7;       // uniform per block
        const int hd = wc + n * 16 + l15;
        if (mat == 0) {
#pragma unroll
          for (int r = 0; r < 4; ++r) {
            const int mm = row0 + r, b = mm >> 11, t = mm & 2047;
            Qb[((size_t)(b * NH + h) * TT + t) * HDIM + hd] =
                f2bf(acc[m][n][r] * RSCALE);
          }
        } else if (mat == 1) {
#pragma unroll
          for (int r = 0; r < 4; ++r) {
            const int mm = row0 + r, b = mm >> 11, t = mm & 2047;
            Kb[((size_t)(b * NH + h) * TT + t) * HDIM + hd] = f2bf(acc[m][n][r]);
          }
        } else {  // V stored transposed: Vt[b,h,hd,t]
          const int b = row0 >> 11, t = row0 & 2047;  // 4 rows share b
          uint2 u;
          u.x = (unsigned)f2bf(acc[m][n][0]) | ((unsigned)f2bf(acc[m][n][1]) << 16);
          u.y = (unsigned)f2bf(acc[m][n][2]) | ((unsigned)f2bf(acc[m][n][3]) << 16);
          *(uint2*)&Vt[((size_t)(b * NH + h) * HDIM + hd) * TT + t] = u;
        }
      }
    }
  }
}

// ------------------------------------------------------------ flash attention
// grid (qtile=32, bh=64), 256 thr = 4 waves, wave handles 16 q rows.
// Q pre-scaled by 1/sqrt(HD).  kv tiles of 32, online softmax.
__global__ __launch_bounds__(256) void attn(const unsigned short* __restrict__ Qb,
                                            const unsigned short* __restrict__ Kb,
                                            const unsigned short* __restrict__ Vt,
                                            unsigned short* __restrict__ O) {
  __shared__ __align__(16) unsigned short pl[4][16][40];  // pad->stride 80B
  const int qt = blockIdx.x;
  const int bh = blockIdx.y;
  const int tid = threadIdx.x;
  const int w = tid >> 6;
  const int lane = tid & 63;
  const int l15 = lane & 15, g = lane >> 4;
  const int q0 = qt * 64 + w * 16;

  const unsigned short* Qh = Qb + (size_t)bh * TT * HDIM;
  const unsigned short* Kh = Kb + (size_t)bh * TT * HDIM;
  const unsigned short* Vh = Vt + (size_t)bh * HDIM * TT;

  bf16x8 qf[4];
#pragma unroll
  for (int kc = 0; kc < 4; ++kc)
    qf[kc] = *(const bf16x8*)&Qh[(size_t)(q0 + l15) * HDIM + kc * 32 + g * 8];

  f32x4 o[8] = {};
  float mrow[4], lrow[4];
#pragma unroll
  for (int r = 0; r < 4; ++r) { mrow[r] = -1e30f; lrow[r] = 0.f; }

  const int kv_end = qt * 64 + 64;
  for (int kv0 = 0; kv0 < kv_end; kv0 += 32) {
    f32x4 s0 = {}, s1 = {};
    const unsigned short* K0 = Kh + (size_t)(kv0 + l15) * HDIM;
    const unsigned short* K1 = K0 + 16 * HDIM;
#pragma unroll
    for (int kc = 0; kc < 4; ++kc) {
      s0 = mfma16(qf[kc], *(const bf16x8*)&K0[kc * 32 + g * 8], s0);
      s1 = mfma16(qf[kc], *(const bf16x8*)&K1[kc * 32 + g * 8], s1);
    }
    // causal mask: element (q = q0+4g+r, kv = kv0 + {0,16} + l15)
    float pmax[4];
#pragma unroll
    for (int r = 0; r < 4; ++r) {
      const int q = q0 + 4 * g + r;
      if (kv0 + l15 > q) s0[r] = -1e30f;
      if (kv0 + 16 + l15 > q) s1[r] = -1e30f;
      pmax[r] = fmaxf(s0[r], s1[r]);
    }
#pragma unroll
    for (int off = 1; off < 16; off <<= 1) {
#pragma unroll
      for (int r = 0; r < 4; ++r)
        pmax[r] = fmaxf(pmax[r], __shfl_xor(pmax[r], off, 64));
    }
    float al[4], rs[4];
#pragma unroll
    for (int r = 0; r < 4; ++r) {
      const float mn = fmaxf(mrow[r], pmax[r]);
      al[r] = __expf(mrow[r] - mn);
      mrow[r] = mn;
      s0[r] = __expf(s0[r] - mn);
      s1[r] = __expf(s1[r] - mn);
      rs[r] = s0[r] + s1[r];
    }
#pragma unroll
    for (int off = 1; off < 16; off <<= 1) {
#pragma unroll
      for (int r = 0; r < 4; ++r) rs[r] += __shfl_xor(rs[r], off, 64);
    }
#pragma unroll
    for (int r = 0; r < 4; ++r) lrow[r] = lrow[r] * al[r] + rs[r];
#pragma unroll
    for (int n8 = 0; n8 < 8; ++n8)
#pragma unroll
      for (int r = 0; r < 4; ++r) o[n8][r] *= al[r];

    // P (f32, C-layout) -> wave-private LDS -> bf16 A-frag
#pragma unroll
    for (int r = 0; r < 4; ++r) {
      pl[w][4 * g + r][l15] = f2bf(s0[r]);
      pl[w][4 * g + r][16 + l15] = f2bf(s1[r]);
    }
    bf16x8 pf = *(const bf16x8*)&pl[w][l15][g * 8];  // compiler emits lgkmcnt
    const unsigned short* V0 = Vh + kv0 + g * 8;
#pragma unroll
    for (int n8 = 0; n8 < 8; ++n8)
      o[n8] = mfma16(pf, *(const bf16x8*)&V0[(size_t)(n8 * 16 + l15) * TT], o[n8]);
  }

  const int b = bh >> 4, h = bh & 15;
  float linv[4];
#pragma unroll
  for (int r = 0; r < 4; ++r) linv[r] = 1.0f / lrow[r];
#pragma unroll
  for (int n8 = 0; n8 < 8; ++n8) {
#pragma unroll
    for (int r = 0; r < 4; ++r) {
      const int q = q0 + 4 * g + r;
      O[((size_t)(b * TT + q)) * (NH * HDIM) + h * HDIM + n8 * 16 + l15] =
          f2bf(o[n8][r] * linv[r]);
    }
  }
}

// ---------------------------------------------------------------------- launch
extern "C" void kernel_launch(void* const* d_in, const int* in_sizes, int n_in,
                              void* d_out, int out_size, void* d_ws, size_t ws_size,
                              hipStream_t stream) {
  const float* x  = (const float*)d_in[0];
  const float* Wq = (const float*)d_in[1];
  const float* Wk = (const float*)d_in[2];
  const float* Wv = (const float*)d_in[3];
  const float* Wo = (const float*)d_in[4];
  float* out = (float*)d_out;

  char* ws = (char*)d_ws;
  size_t off = 0;
  unsigned short* xb  = (unsigned short*)(ws + off); off += (size_t)MSZ * DD * 2;   // 32 MiB (reused as O)
  unsigned short* Wtq = (unsigned short*)(ws + off); off += (size_t)NQKV * DD * 2;  // 24 MiB
  unsigned short* Wto = (unsigned short*)(ws + off); off += (size_t)DD * DD * 2;    // 8 MiB
  unsigned short* Qb  = (unsigned short*)(ws + off); off += (size_t)MSZ * DD * 2;   // 32 MiB
  unsigned short* Kb  = (unsigned short*)(ws + off); off += (size_t)MSZ * DD * 2;   // 32 MiB
  unsigned short* Vt  = (unsigned short*)(ws + off); off += (size_t)MSZ * DD * 2;   // 32 MiB
  unsigned short* Ob  = xb;  // x_bf16 dead after QKV GEMM -> reuse for attn out

  cvtx<<<2048, 256, 0, stream>>>(x, xb);
  transW<<<dim3(64, 64, 4), 256, 0, stream>>>(Wq, Wk, Wv, Wo, Wtq, Wto);
  gemm_bt<0><<<dim3(NQKV / 128, MSZ / 128), 256, 0, stream>>>(xb, Wtq, Qb, Kb, Vt, nullptr);
  attn<<<dim3(TT / 64, NB * NH), 256, 0, stream>>>(Qb, Kb, Vt, Ob);
  gemm_bt<1><<<dim3(DD / 128, MSZ / 128), 256, 0, stream>>>(Ob, Wto, nullptr, nullptr, nullptr, out);
}

// Round 3
// 732.800 us; speedup vs baseline: 1.9497x; 1.9497x over previous
//
#include <hip/hip_runtime.h>
#include <hip/hip_bf16.h>
#include <stdint.h>

// Problem: B=4, T=2048, D=2048, H=16, HD=128.  out = Attn(xWq, xWk, xWv) Wo
#define TT   2048
#define DD   2048
#define NH   16
#define NB   4
#define HDIM 128
#define MSZ  (NB * TT)      // 8192 rows for the token-major GEMMs
#define NQKV (3 * DD)       // 6144 fused QKV output columns

typedef __attribute__((ext_vector_type(8))) __bf16 bf16x8;
typedef __attribute__((ext_vector_type(4))) float  f32x4;

typedef __attribute__((address_space(3))) void       lds_void;
typedef const __attribute__((address_space(1))) void g_void;

__device__ inline unsigned short f2bf(float f) {
  union { float f; unsigned u; } v; v.f = f;
  unsigned r = v.u + 0x7fffu + ((v.u >> 16) & 1u);  // round-to-nearest-even
  return (unsigned short)(r >> 16);
}

__device__ inline void gload16(const void* g, void* l) {
  __builtin_amdgcn_global_load_lds((g_void*)g, (lds_void*)l, 16, 0, 0);
}

__device__ inline f32x4 mfma16(bf16x8 a, bf16x8 b, f32x4 c) {
  return __builtin_amdgcn_mfma_f32_16x16x32_bf16(a, b, c, 0, 0, 0);
}

// ---------------------------------------------------------------- cvt x->bf16
__global__ __launch_bounds__(256) void cvtx(const float* __restrict__ x,
                                            unsigned short* __restrict__ xb) {
  const int n4 = MSZ * DD / 4;
  for (int i = blockIdx.x * blockDim.x + threadIdx.x; i < n4;
       i += gridDim.x * blockDim.x) {
    float4 v = ((const float4*)x)[i];
    uint2 u;
    u.x = (unsigned)f2bf(v.x) | ((unsigned)f2bf(v.y) << 16);
    u.y = (unsigned)f2bf(v.z) | ((unsigned)f2bf(v.w) << 16);
    *(uint2*)&xb[(size_t)i * 4] = u;
  }
}

// ------------------------------------------- W (K,N) f32 -> Wt (N,K) bf16
__global__ __launch_bounds__(256) void transW(const float* __restrict__ Wq,
                                              const float* __restrict__ Wk,
                                              const float* __restrict__ Wv,
                                              const float* __restrict__ Wo,
                                              unsigned short* __restrict__ Wtq,
                                              unsigned short* __restrict__ Wto) {
  __shared__ float tl[32][33];
  const int z = blockIdx.z;
  const float* W = (z == 0) ? Wq : (z == 1) ? Wk : (z == 2) ? Wv : Wo;
  unsigned short* outp = (z < 3) ? (Wtq + (size_t)z * DD * DD) : Wto;
  const int c = threadIdx.x & 31, r8 = threadIdx.x >> 5;
  const int k0 = blockIdx.y * 32, n0 = blockIdx.x * 32;
#pragma unroll
  for (int i = 0; i < 4; ++i)
    tl[r8 + 8 * i][c] = W[(size_t)(k0 + r8 + 8 * i) * DD + n0 + c];
  __syncthreads();
#pragma unroll
  for (int i = 0; i < 4; ++i)
    outp[(size_t)(n0 + r8 + 8 * i) * DD + k0 + c] = f2bf(tl[c][r8 + 8 * i]);
}

// --------------------------------------------------------------- GEMM (B^T)
// C[M,N] = A[M,K] * Bt[N,K]^T, K = 2048, 128x128 tile, 4 waves of 64x64.
// EPI 0: fused-QKV epilogue (Q scaled, K normal, V transposed), bf16 out.
// EPI 1: plain f32 store to Cf (the final projection, writes d_out).
template <int EPI>
__global__ __launch_bounds__(256) void gemm_bt(
    const unsigned short* __restrict__ A, const unsigned short* __restrict__ Bt,
    unsigned short* __restrict__ Qb, unsigned short* __restrict__ Kb,
    unsigned short* __restrict__ Vt, float* __restrict__ Cf) {
  __shared__ __align__(16) unsigned short As[128 * 32];
  __shared__ __align__(16) unsigned short Bs[128 * 32];
  const int tid = threadIdx.x;
  const int m0 = blockIdx.y * 128;
  const int n0 = blockIdx.x * 128;
  const int lane = tid & 63;
  const int w = tid >> 6;
  const int wr = (w >> 1) * 64;
  const int wc = (w & 1) * 64;
  const int l15 = lane & 15;
  const int g = lane >> 4;

  const unsigned short* gA0 = A + (size_t)(m0 + (tid >> 2)) * DD + (tid & 3) * 8;
  const unsigned short* gA1 = gA0 + (size_t)64 * DD;
  const unsigned short* gB0 = Bt + (size_t)(n0 + (tid >> 2)) * DD + (tid & 3) * 8;
  const unsigned short* gB1 = gB0 + (size_t)64 * DD;
  unsigned short* lA0 = &As[tid * 8];
  unsigned short* lA1 = &As[(tid + 256) * 8];
  unsigned short* lB0 = &Bs[tid * 8];
  unsigned short* lB1 = &Bs[(tid + 256) * 8];

  f32x4 acc[4][4] = {};

  for (int ks = 0; ks < DD / 32; ++ks) {
    __syncthreads();  // prior iter's LDS reads complete
    gload16(gA0, lA0); gload16(gA1, lA1);
    gload16(gB0, lB0); gload16(gB1, lB1);
    gA0 += 32; gA1 += 32; gB0 += 32; gB1 += 32;
    __syncthreads();  // drains vmcnt -> tiles resident

    bf16x8 afr[4], bfr[4];
#pragma unroll
    for (int m = 0; m < 4; ++m)
      afr[m] = *(const bf16x8*)&As[(wr + m * 16 + l15) * 32 + g * 8];
#pragma unroll
    for (int n = 0; n < 4; ++n)
      bfr[n] = *(const bf16x8*)&Bs[(wc + n * 16 + l15) * 32 + g * 8];
#pragma unroll
    for (int m = 0; m < 4; ++m)
#pragma unroll
      for (int n = 0; n < 4; ++n)
        acc[m][n] = mfma16(afr[m], bfr[n], acc[m][n]);
  }

  // Epilogue. C frag: row = 4*g + r, col = l15 (m89-verified mapping).
  const float RSCALE = 0.08838834764831845f;  // 1/sqrt(HD)
#pragma unroll
  for (int m = 0; m < 4; ++m) {
#pragma unroll
    for (int n = 0; n < 4; ++n) {
      const int row0 = m0 + wr + m * 16 + 4 * g;
      const int col = n0 + wc + n * 16 + l15;
      if (EPI == 1) {
#pragma unroll
        for (int r = 0; r < 4; ++r)
          Cf[(size_t)(row0 + r) * DD + col] = acc[m][n][r];
      } else {
        const int mat = n0 >> 11;             // uniform per block
        const int h = (n0 & 2047) >> 7;       // uniform per block
        const int hd = wc + n * 16 + l15;
        if (mat == 0) {
#pragma unroll
          for (int r = 0; r < 4; ++r) {
            const int mm = row0 + r, b = mm >> 11, t = mm & 2047;
            Qb[((size_t)(b * NH + h) * TT + t) * HDIM + hd] =
                f2bf(acc[m][n][r] * RSCALE);
          }
        } else if (mat == 1) {
#pragma unroll
          for (int r = 0; r < 4; ++r) {
            const int mm = row0 + r, b = mm >> 11, t = mm & 2047;
            Kb[((size_t)(b * NH + h) * TT + t) * HDIM + hd] = f2bf(acc[m][n][r]);
          }
        } else {  // V stored transposed: Vt[b,h,hd,t]
          const int b = row0 >> 11, t = row0 & 2047;  // 4 rows share b
          uint2 u;
          u.x = (unsigned)f2bf(acc[m][n][0]) | ((unsigned)f2bf(acc[m][n][1]) << 16);
          u.y = (unsigned)f2bf(acc[m][n][2]) | ((unsigned)f2bf(acc[m][n][3]) << 16);
          *(uint2*)&Vt[((size_t)(b * NH + h) * HDIM + hd) * TT + t] = u;
        }
      }
    }
  }
}

// ------------------------------------------------------------ flash attention
// grid (16, 64), 256 thr = 4 waves.  Block bx processes q-tiles {31-bx, bx}
// (causal pairing -> uniform 66 kv-tiles/block).  K/V tiles cooperatively
// staged in double-buffered LDS via global_load_lds (blocked 16B-unit
// layouts, bank-conflict free).  Q pre-scaled by 1/sqrt(HD).
__global__ __launch_bounds__(256, 4) void attn(const unsigned short* __restrict__ Qb,
                                               const unsigned short* __restrict__ Kb,
                                               const unsigned short* __restrict__ Vt,
                                               unsigned short* __restrict__ O) {
  // K tile: 32 kv-rows x 128 hd.  16B unit index = ch*32 + row, ch = hd-chunk.
  // V tile: 128 hd-rows x 32 kv.  16B unit index = c*128 + row, c = kv-chunk.
  __shared__ __align__(16) unsigned short Ks[2][4096];
  __shared__ __align__(16) unsigned short Vs[2][4096];
  __shared__ __align__(16) unsigned short pl[4][16][40];  // P bounce, pad 40

  const int bx = blockIdx.x;   // 0..15
  const int bh = blockIdx.y;
  const int tid = threadIdx.x;
  const int w = tid >> 6;
  const int lane = tid & 63;
  const int l15 = lane & 15, g = lane >> 4;

  const unsigned short* Qh = Qb + (size_t)bh * TT * HDIM;
  const unsigned short* Kh = Kb + (size_t)bh * TT * HDIM;
  const unsigned short* Vh = Vt + (size_t)bh * HDIM * TT;
  const int b = bh >> 4, h = bh & 15;

  // staging constants: thread -> 16B unit == tid (round 0) / tid+256 (round 1)
  const int kch = tid >> 5, krow = tid & 31;    // K: unit = ch*32+row
  const int vc = tid >> 7, vrow = tid & 127;    // V: unit = c*128+row

  int buf = 0;
#pragma unroll 1
  for (int ph = 0; ph < 2; ++ph) {
    const int qt = ph ? bx : (31 - bx);
    const int q0 = qt * 64 + w * 16;
    const int nt = 2 * qt + 2;

    bf16x8 qf[4];
#pragma unroll
    for (int kc = 0; kc < 4; ++kc)
      qf[kc] = *(const bf16x8*)&Qh[(size_t)(q0 + l15) * HDIM + kc * 32 + g * 8];

    f32x4 o[8] = {};
    float mrow[4], lrow[4];
#pragma unroll
    for (int r = 0; r < 4; ++r) { mrow[r] = -1e30f; lrow[r] = 0.f; }

    // prologue: stage tile 0
    {
      const int kv0 = 0;
      gload16(Kh + (size_t)(kv0 + krow) * HDIM + kch * 8,      &Ks[buf][(kch * 32 + krow) * 8]);
      gload16(Kh + (size_t)(kv0 + krow) * HDIM + (kch + 8) * 8,&Ks[buf][((kch + 8) * 32 + krow) * 8]);
      gload16(Vh + (size_t)vrow * TT + kv0 + vc * 8,           &Vs[buf][(vc * 128 + vrow) * 8]);
      gload16(Vh + (size_t)vrow * TT + kv0 + (vc + 2) * 8,     &Vs[buf][((vc + 2) * 128 + vrow) * 8]);
    }

#pragma unroll 1
    for (int t = 0; t < nt; ++t) {
      const int kv0 = t * 32;
      __syncthreads();  // vmcnt drained -> tile t resident in buf
      if (t + 1 < nt) {
        const int kvn = kv0 + 32;
        gload16(Kh + (size_t)(kvn + krow) * HDIM + kch * 8,      &Ks[buf ^ 1][(kch * 32 + krow) * 8]);
        gload16(Kh + (size_t)(kvn + krow) * HDIM + (kch + 8) * 8,&Ks[buf ^ 1][((kch + 8) * 32 + krow) * 8]);
        gload16(Vh + (size_t)vrow * TT + kvn + vc * 8,           &Vs[buf ^ 1][(vc * 128 + vrow) * 8]);
        gload16(Vh + (size_t)vrow * TT + kvn + (vc + 2) * 8,     &Vs[buf ^ 1][((vc + 2) * 128 + vrow) * 8]);
      }

      if (kv0 <= q0 + 15) {  // skip fully-masked tiles (barriers still honored)
        f32x4 s0 = {}, s1 = {};
#pragma unroll
        for (int kc = 0; kc < 4; ++kc) {
          bf16x8 k0 = *(const bf16x8*)&Ks[buf][((kc * 4 + g) * 32 + l15) * 8];
          bf16x8 k1 = *(const bf16x8*)&Ks[buf][((kc * 4 + g) * 32 + 16 + l15) * 8];
          s0 = mfma16(qf[kc], k0, s0);
          s1 = mfma16(qf[kc], k1, s1);
        }
        // causal mask: element (q = q0+4g+r, kv = kv0 + {0,16} + l15)
        float pmax[4];
#pragma unroll
        for (int r = 0; r < 4; ++r) {
          const int q = q0 + 4 * g + r;
          if (kv0 + l15 > q) s0[r] = -1e30f;
          if (kv0 + 16 + l15 > q) s1[r] = -1e30f;
          pmax[r] = fmaxf(s0[r], s1[r]);
        }
#pragma unroll
        for (int off = 1; off < 16; off <<= 1) {
#pragma unroll
          for (int r = 0; r < 4; ++r)
            pmax[r] = fmaxf(pmax[r], __shfl_xor(pmax[r], off, 64));
        }
        float al[4], rs[4];
#pragma unroll
        for (int r = 0; r < 4; ++r) {
          const float mn = fmaxf(mrow[r], pmax[r]);
          al[r] = __expf(mrow[r] - mn);
          mrow[r] = mn;
          s0[r] = __expf(s0[r] - mn);
          s1[r] = __expf(s1[r] - mn);
          rs[r] = s0[r] + s1[r];
        }
#pragma unroll
        for (int off = 1; off < 16; off <<= 1) {
#pragma unroll
          for (int r = 0; r < 4; ++r) rs[r] += __shfl_xor(rs[r], off, 64);
        }
#pragma unroll
        for (int r = 0; r < 4; ++r) lrow[r] = lrow[r] * al[r] + rs[r];
#pragma unroll
        for (int n8 = 0; n8 < 8; ++n8)
#pragma unroll
          for (int r = 0; r < 4; ++r) o[n8][r] *= al[r];

        // P (f32, C-layout) -> wave-private LDS -> bf16 A-frag
#pragma unroll
        for (int r = 0; r < 4; ++r) {
          pl[w][4 * g + r][l15] = f2bf(s0[r]);
          pl[w][4 * g + r][16 + l15] = f2bf(s1[r]);
        }
        bf16x8 pf = *(const bf16x8*)&pl[w][l15][g * 8];  // compiler emits lgkmcnt
#pragma unroll
        for (int n8 = 0; n8 < 8; ++n8) {
          bf16x8 vf = *(const bf16x8*)&Vs[buf][(g * 128 + n8 * 16 + l15) * 8];
          o[n8] = mfma16(pf, vf, o[n8]);
        }
      }
      __syncthreads();  // all waves done with buf before overwrite
      buf ^= 1;
    }

    float linv[4];
#pragma unroll
    for (int r = 0; r < 4; ++r) linv[r] = 1.0f / lrow[r];
#pragma unroll
    for (int n8 = 0; n8 < 8; ++n8) {
#pragma unroll
      for (int r = 0; r < 4; ++r) {
        const int q = q0 + 4 * g + r;
        O[((size_t)(b * TT + q)) * (NH * HDIM) + h * HDIM + n8 * 16 + l15] =
            f2bf(o[n8][r] * linv[r]);
      }
    }
  }
}

// ---------------------------------------------------------------------- launch
extern "C" void kernel_launch(void* const* d_in, const int* in_sizes, int n_in,
                              void* d_out, int out_size, void* d_ws, size_t ws_size,
                              hipStream_t stream) {
  const float* x  = (const float*)d_in[0];
  const float* Wq = (const float*)d_in[1];
  const float* Wk = (const float*)d_in[2];
  const float* Wv = (const float*)d_in[3];
  const float* Wo = (const float*)d_in[4];
  float* out = (float*)d_out;

  char* ws = (char*)d_ws;
  size_t off = 0;
  unsigned short* xb  = (unsigned short*)(ws + off); off += (size_t)MSZ * DD * 2;   // 32 MiB (reused as O)
  unsigned short* Wtq = (unsigned short*)(ws + off); off += (size_t)NQKV * DD * 2;  // 24 MiB
  unsigned short* Wto = (unsigned short*)(ws + off); off += (size_t)DD * DD * 2;    // 8 MiB
  unsigned short* Qb  = (unsigned short*)(ws + off); off += (size_t)MSZ * DD * 2;   // 32 MiB
  unsigned short* Kb  = (unsigned short*)(ws + off); off += (size_t)MSZ * DD * 2;   // 32 MiB
  unsigned short* Vt  = (unsigned short*)(ws + off); off += (size_t)MSZ * DD * 2;   // 32 MiB
  unsigned short* Ob  = xb;  // x_bf16 dead after QKV GEMM -> reuse for attn out

  cvtx<<<2048, 256, 0, stream>>>(x, xb);
  transW<<<dim3(64, 64, 4), 256, 0, stream>>>(Wq, Wk, Wv, Wo, Wtq, Wto);
  gemm_bt<0><<<dim3(NQKV / 128, MSZ / 128), 256, 0, stream>>>(xb, Wtq, Qb, Kb, Vt, nullptr);
  attn<<<dim3(16, NB * NH), 256, 0, stream>>>(Qb, Kb, Vt, Ob);
  gemm_bt<1><<<dim3(DD / 128, MSZ / 128), 256, 0, stream>>>(Ob, Wto, nullptr, nullptr, nullptr, out);
}

// Round 4
// 627.101 us; speedup vs baseline: 2.2783x; 1.1686x over previous
//
#include <hip/hip_runtime.h>
#include <hip/hip_bf16.h>
#include <stdint.h>

// Problem: B=4, T=2048, D=2048, H=16, HD=128.  out = Attn(xWq, xWk, xWv) Wo
#define TT   2048
#define DD   2048
#define NH   16
#define NB   4
#define HDIM 128
#define MSZ  (NB * TT)      // 8192 rows for the token-major GEMMs
#define NQKV (3 * DD)       // 6144 fused QKV output columns
#define NT   32             // K tiles of 64: 2048/64

typedef __attribute__((ext_vector_type(8))) __bf16 bf16x8;
typedef __attribute__((ext_vector_type(4))) float  f32x4;

typedef __attribute__((address_space(3))) void       lds_void;
typedef const __attribute__((address_space(1))) void g_void;

__device__ inline unsigned short f2bf(float f) {
  union { float f; unsigned u; } v; v.f = f;
  unsigned r = v.u + 0x7fffu + ((v.u >> 16) & 1u);  // round-to-nearest-even
  return (unsigned short)(r >> 16);
}

__device__ inline void gload16(const void* g, void* l) {
  __builtin_amdgcn_global_load_lds((g_void*)g, (lds_void*)l, 16, 0, 0);
}

__device__ inline f32x4 mfma16(bf16x8 a, bf16x8 b, f32x4 c) {
  return __builtin_amdgcn_mfma_f32_16x16x32_bf16(a, b, c, 0, 0, 0);
}

// ---------------------------------------------------------------- cvt x->bf16
__global__ __launch_bounds__(256) void cvtx(const float* __restrict__ x,
                                            unsigned short* __restrict__ xb) {
  const int n4 = MSZ * DD / 4;
  for (int i = blockIdx.x * blockDim.x + threadIdx.x; i < n4;
       i += gridDim.x * blockDim.x) {
    float4 v = ((const float4*)x)[i];
    uint2 u;
    u.x = (unsigned)f2bf(v.x) | ((unsigned)f2bf(v.y) << 16);
    u.y = (unsigned)f2bf(v.z) | ((unsigned)f2bf(v.w) << 16);
    *(uint2*)&xb[(size_t)i * 4] = u;
  }
}

// ------------------------------------------- W (K,N) f32 -> Wt (N,K) bf16
__global__ __launch_bounds__(256) void transW(const float* __restrict__ Wq,
                                              const float* __restrict__ Wk,
                                              const float* __restrict__ Wv,
                                              const float* __restrict__ Wo,
                                              unsigned short* __restrict__ Wtq,
                                              unsigned short* __restrict__ Wto) {
  __shared__ float tl[32][33];
  const int z = blockIdx.z;
  const float* W = (z == 0) ? Wq : (z == 1) ? Wk : (z == 2) ? Wv : Wo;
  unsigned short* outp = (z < 3) ? (Wtq + (size_t)z * DD * DD) : Wto;
  const int c = threadIdx.x & 31, r8 = threadIdx.x >> 5;
  const int k0 = blockIdx.y * 32, n0 = blockIdx.x * 32;
#pragma unroll
  for (int i = 0; i < 4; ++i)
    tl[r8 + 8 * i][c] = W[(size_t)(k0 + r8 + 8 * i) * DD + n0 + c];
  __syncthreads();
#pragma unroll
  for (int i = 0; i < 4; ++i)
    outp[(size_t)(n0 + r8 + 8 * i) * DD + k0 + c] = f2bf(tl[c][r8 + 8 * i]);
}

// ------------------------------------------------- 256x256 8-phase GEMM (B^T)
// C[M,N] = A[M,K] * Bt[N,K]^T, K = 2048.  512 thr = 8 waves (2M x 4N), each
// wave owns 128x64 of C.  BK=64; LDS = 2 dbuf x 2 half x 128x64 x {A,B} x 2B
// = 128 KiB.  Half layout: [ch(2)][row(128)][col(32)] bf16, phys byte =
// logical ^ ((bit9)<<5) (st_16x32 swizzle; linear gload dest + pre-swizzled
// global src + swizzled ds_read).  Per tile: 4 phases x {stage 1 half,
// barrier, 16 MFMA, barrier}; all 24 frag ds_reads in phase 0 (pinned by
// lgkmcnt(0) asm); vmcnt(6) once per tile (3 half-tiles in flight).
template <int EPI>
__global__ __launch_bounds__(512, 2) void gemm8(
    const unsigned short* __restrict__ A, const unsigned short* __restrict__ Bt,
    unsigned short* __restrict__ Qb, unsigned short* __restrict__ Kb,
    unsigned short* __restrict__ Vt, float* __restrict__ Cf) {
  __shared__ __align__(16) unsigned short As[2][2][8192];
  __shared__ __align__(16) unsigned short Bs[2][2][8192];
  const int tid = threadIdx.x;
  const int lane = tid & 63;
  const int w = tid >> 6;
  const int wm = w >> 2, wn = w & 3;
  const int l15 = lane & 15, g = lane >> 4;
  const int m0 = blockIdx.y * 256, n0 = blockIdx.x * 256;

  // staging: thread writes linear LDS bytes [tid*16 .. +16) (+8KiB for j=1);
  // content there must be logical offset u = swz(dest).
  const int u  = (tid * 16) ^ (((tid >> 5) & 1) << 5);
  const int sr = (u >> 6) & 127;     // row within half
  const int sc = (u & 63) >> 1;      // col within 32-chunk
  const unsigned short* sA0 = A  + (size_t)(m0 + sr) * DD + sc;
  const unsigned short* sA1 = A  + (size_t)(m0 + 128 + sr) * DD + sc;
  const unsigned short* sB0 = Bt + (size_t)(n0 + sr) * DD + sc;
  const unsigned short* sB1 = Bt + (size_t)(n0 + 128 + sr) * DD + sc;

  // frag read base (ushort idx): swizzle bit depends only on l15 bit3.
  const int pA = ((l15 * 64 + g * 16) ^ (((l15 >> 3) & 1) << 5)) >> 1;
  const int pB = (wn & 1) * 2048 + pA;

  f32x4 acc[8][4] = {};

#define STAGE(kt, hf)                                                         \
  do {                                                                        \
    if ((kt) < NT) {                                                          \
      const unsigned short* s_ = (hf) == 0 ? sA0 : (hf) == 1 ? sA1            \
                                 : (hf) == 2 ? sB0 : sB1;                     \
      s_ += (kt) * 64;                                                        \
      unsigned short* d_ = ((hf) < 2 ? &As[(kt) & 1][(hf) & 1][0]             \
                                     : &Bs[(kt) & 1][(hf) & 1][0]) + tid * 8; \
      gload16(s_, d_);                                                        \
      gload16(s_ + 32, d_ + 4096);                                            \
    }                                                                         \
  } while (0)

#define MFMAQ(q)                                                              \
  do {                                                                        \
    __builtin_amdgcn_s_setprio(1);                                            \
    _Pragma("unroll") for (int n2 = 0; n2 < 2; ++n2)                          \
    _Pragma("unroll") for (int m2 = 0; m2 < 4; ++m2)                          \
    _Pragma("unroll") for (int kk = 0; kk < 2; ++kk)                          \
      acc[((q) & 1) * 4 + m2][((q) >> 1) * 2 + n2] =                          \
          mfma16(af[((q) & 1) * 4 + m2][kk], bq[((q) >> 1) * 2 + n2][kk],     \
                 acc[((q) & 1) * 4 + m2][((q) >> 1) * 2 + n2]);               \
    __builtin_amdgcn_s_setprio(0);                                            \
  } while (0)

#define TILE(t, buf)                                                          \
  do {                                                                        \
    const unsigned short* Ab = &As[buf][wm][0];                               \
    const unsigned short* Bb = &Bs[buf][wn >> 1][0];                          \
    bf16x8 af[8][2], bq[4][2];                                                \
    _Pragma("unroll") for (int m = 0; m < 8; ++m) {                           \
      af[m][0] = *(const bf16x8*)&Ab[pA + m * 512];                           \
      af[m][1] = *(const bf16x8*)&Ab[pA + m * 512 + 4096];                    \
    }                                                                         \
    _Pragma("unroll") for (int n = 0; n < 4; ++n) {                           \
      bq[n][0] = *(const bf16x8*)&Bb[pB + n * 512];                           \
      bq[n][1] = *(const bf16x8*)&Bb[pB + n * 512 + 4096];                    \
    }                                                                         \
    STAGE((t) + 1, 3);                                                        \
    __builtin_amdgcn_s_barrier();                                             \
    MFMAQ(0);                                                                 \
    asm volatile("s_waitcnt lgkmcnt(0)" ::: "memory");                        \
    __builtin_amdgcn_sched_barrier(0);                                        \
    __builtin_amdgcn_s_barrier();                                             \
    STAGE((t) + 2, 0);                                                        \
    __builtin_amdgcn_s_barrier();                                             \
    MFMAQ(1);                                                                 \
    __builtin_amdgcn_s_barrier();                                             \
    STAGE((t) + 2, 1);                                                        \
    __builtin_amdgcn_s_barrier();                                             \
    MFMAQ(2);                                                                 \
    __builtin_amdgcn_s_barrier();                                             \
    STAGE((t) + 2, 2);                                                        \
    __builtin_amdgcn_s_barrier();                                             \
    MFMAQ(3);                                                                 \
    asm volatile("s_waitcnt vmcnt(6)" ::: "memory");                          \
    __builtin_amdgcn_sched_barrier(0);                                        \
    __builtin_amdgcn_s_barrier();                                             \
  } while (0)

  // prologue: tile0 fully + tile1 halves 0-2 (h3 staged at P(0,0)).
  STAGE(0, 0); STAGE(0, 1); STAGE(0, 2); STAGE(0, 3);
  STAGE(1, 0); STAGE(1, 1); STAGE(1, 2);
  asm volatile("s_waitcnt vmcnt(6)" ::: "memory");
  __builtin_amdgcn_sched_barrier(0);
  __builtin_amdgcn_s_barrier();

#pragma unroll 1
  for (int it = 0; it < NT / 2; ++it) {
    TILE(2 * it, 0);
    TILE(2 * it + 1, 1);
  }
#undef TILE
#undef MFMAQ
#undef STAGE

  // Epilogue. C frag: row = 4*g + r, col = l15 (m89-verified mapping).
  const float RSCALE = 0.08838834764831845f;  // 1/sqrt(HD)
#pragma unroll
  for (int m = 0; m < 8; ++m) {
#pragma unroll
    for (int n = 0; n < 4; ++n) {
      const int row0 = m0 + wm * 128 + m * 16 + 4 * g;
      const int col2 = wn * 64 + n * 16;
      const int col = n0 + col2 + l15;
      if (EPI == 1) {
#pragma unroll
        for (int r = 0; r < 4; ++r)
          Cf[(size_t)(row0 + r) * DD + col] = acc[m][n][r];
      } else {
        const int mat = n0 >> 11;                    // uniform per block
        const int h = ((n0 & 2047) + col2) >> 7;     // uniform per (wave,n)
        const int hd = (col2 & 127) + l15;
        if (mat == 0) {
#pragma unroll
          for (int r = 0; r < 4; ++r) {
            const int mm = row0 + r, b = mm >> 11, t = mm & 2047;
            Qb[((size_t)(b * NH + h) * TT + t) * HDIM + hd] =
                f2bf(acc[m][n][r] * RSCALE);
          }
        } else if (mat == 1) {
#pragma unroll
          for (int r = 0; r < 4; ++r) {
            const int mm = row0 + r, b = mm >> 11, t = mm & 2047;
            Kb[((size_t)(b * NH + h) * TT + t) * HDIM + hd] = f2bf(acc[m][n][r]);
          }
        } else {  // V stored transposed: Vt[b,h,hd,t]
          const int b = row0 >> 11, t = row0 & 2047;  // 4 rows share b
          uint2 uu;
          uu.x = (unsigned)f2bf(acc[m][n][0]) | ((unsigned)f2bf(acc[m][n][1]) << 16);
          uu.y = (unsigned)f2bf(acc[m][n][2]) | ((unsigned)f2bf(acc[m][n][3]) << 16);
          *(uint2*)&Vt[((size_t)(b * NH + h) * HDIM + hd) * TT + t] = uu;
        }
      }
    }
  }
}

// ------------------------------------------------------------ flash attention
// grid (16, 64), 256 thr = 4 waves.  Block bx processes q-tiles {31-bx, bx}
// (causal pairing -> uniform 66 kv-tiles/block).  K/V tiles cooperatively
// staged in double-buffered LDS via global_load_lds (blocked 16B-unit
// layouts, bank-conflict free).  Q pre-scaled by 1/sqrt(HD).
__global__ __launch_bounds__(256, 4) void attn(const unsigned short* __restrict__ Qb,
                                               const unsigned short* __restrict__ Kb,
                                               const unsigned short* __restrict__ Vt,
                                               unsigned short* __restrict__ O) {
  // K tile: 32 kv-rows x 128 hd.  16B unit index = ch*32 + row, ch = hd-chunk.
  // V tile: 128 hd-rows x 32 kv.  16B unit index = c*128 + row, c = kv-chunk.
  __shared__ __align__(16) unsigned short Ks[2][4096];
  __shared__ __align__(16) unsigned short Vs[2][4096];
  __shared__ __align__(16) unsigned short pl[4][16][40];  // P bounce, pad 40

  const int bx = blockIdx.x;   // 0..15
  const int bh = blockIdx.y;
  const int tid = threadIdx.x;
  const int w = tid >> 6;
  const int lane = tid & 63;
  const int l15 = lane & 15, g = lane >> 4;

  const unsigned short* Qh = Qb + (size_t)bh * TT * HDIM;
  const unsigned short* Kh = Kb + (size_t)bh * TT * HDIM;
  const unsigned short* Vh = Vt + (size_t)bh * HDIM * TT;
  const int b = bh >> 4, h = bh & 15;

  // staging constants: thread -> 16B unit == tid (round 0) / tid+256 (round 1)
  const int kch = tid >> 5, krow = tid & 31;    // K: unit = ch*32+row
  const int vc = tid >> 7, vrow = tid & 127;    // V: unit = c*128+row

  int buf = 0;
#pragma unroll 1
  for (int ph = 0; ph < 2; ++ph) {
    const int qt = ph ? bx : (31 - bx);
    const int q0 = qt * 64 + w * 16;
    const int nt = 2 * qt + 2;

    bf16x8 qf[4];
#pragma unroll
    for (int kc = 0; kc < 4; ++kc)
      qf[kc] = *(const bf16x8*)&Qh[(size_t)(q0 + l15) * HDIM + kc * 32 + g * 8];

    f32x4 o[8] = {};
    float mrow[4], lrow[4];
#pragma unroll
    for (int r = 0; r < 4; ++r) { mrow[r] = -1e30f; lrow[r] = 0.f; }

    // prologue: stage tile 0
    {
      const int kv0 = 0;
      gload16(Kh + (size_t)(kv0 + krow) * HDIM + kch * 8,      &Ks[buf][(kch * 32 + krow) * 8]);
      gload16(Kh + (size_t)(kv0 + krow) * HDIM + (kch + 8) * 8,&Ks[buf][((kch + 8) * 32 + krow) * 8]);
      gload16(Vh + (size_t)vrow * TT + kv0 + vc * 8,           &Vs[buf][(vc * 128 + vrow) * 8]);
      gload16(Vh + (size_t)vrow * TT + kv0 + (vc + 2) * 8,     &Vs[buf][((vc + 2) * 128 + vrow) * 8]);
    }

#pragma unroll 1
    for (int t = 0; t < nt; ++t) {
      const int kv0 = t * 32;
      __syncthreads();  // vmcnt drained -> tile t resident in buf
      if (t + 1 < nt) {
        const int kvn = kv0 + 32;
        gload16(Kh + (size_t)(kvn + krow) * HDIM + kch * 8,      &Ks[buf ^ 1][(kch * 32 + krow) * 8]);
        gload16(Kh + (size_t)(kvn + krow) * HDIM + (kch + 8) * 8,&Ks[buf ^ 1][((kch + 8) * 32 + krow) * 8]);
        gload16(Vh + (size_t)vrow * TT + kvn + vc * 8,           &Vs[buf ^ 1][(vc * 128 + vrow) * 8]);
        gload16(Vh + (size_t)vrow * TT + kvn + (vc + 2) * 8,     &Vs[buf ^ 1][((vc + 2) * 128 + vrow) * 8]);
      }

      if (kv0 <= q0 + 15) {  // skip fully-masked tiles (barriers still honored)
        f32x4 s0 = {}, s1 = {};
#pragma unroll
        for (int kc = 0; kc < 4; ++kc) {
          bf16x8 k0 = *(const bf16x8*)&Ks[buf][((kc * 4 + g) * 32 + l15) * 8];
          bf16x8 k1 = *(const bf16x8*)&Ks[buf][((kc * 4 + g) * 32 + 16 + l15) * 8];
          s0 = mfma16(qf[kc], k0, s0);
          s1 = mfma16(qf[kc], k1, s1);
        }
        // causal mask: element (q = q0+4g+r, kv = kv0 + {0,16} + l15)
        float pmax[4];
#pragma unroll
        for (int r = 0; r < 4; ++r) {
          const int q = q0 + 4 * g + r;
          if (kv0 + l15 > q) s0[r] = -1e30f;
          if (kv0 + 16 + l15 > q) s1[r] = -1e30f;
          pmax[r] = fmaxf(s0[r], s1[r]);
        }
#pragma unroll
        for (int off = 1; off < 16; off <<= 1) {
#pragma unroll
          for (int r = 0; r < 4; ++r)
            pmax[r] = fmaxf(pmax[r], __shfl_xor(pmax[r], off, 64));
        }
        float al[4], rs[4];
#pragma unroll
        for (int r = 0; r < 4; ++r) {
          const float mn = fmaxf(mrow[r], pmax[r]);
          al[r] = __expf(mrow[r] - mn);
          mrow[r] = mn;
          s0[r] = __expf(s0[r] - mn);
          s1[r] = __expf(s1[r] - mn);
          rs[r] = s0[r] + s1[r];
        }
#pragma unroll
        for (int off = 1; off < 16; off <<= 1) {
#pragma unroll
          for (int r = 0; r < 4; ++r) rs[r] += __shfl_xor(rs[r], off, 64);
        }
#pragma unroll
        for (int r = 0; r < 4; ++r) lrow[r] = lrow[r] * al[r] + rs[r];
#pragma unroll
        for (int n8 = 0; n8 < 8; ++n8)
#pragma unroll
          for (int r = 0; r < 4; ++r) o[n8][r] *= al[r];

        // P (f32, C-layout) -> wave-private LDS -> bf16 A-frag
#pragma unroll
        for (int r = 0; r < 4; ++r) {
          pl[w][4 * g + r][l15] = f2bf(s0[r]);
          pl[w][4 * g + r][16 + l15] = f2bf(s1[r]);
        }
        bf16x8 pf = *(const bf16x8*)&pl[w][l15][g * 8];  // compiler emits lgkmcnt
#pragma unroll
        for (int n8 = 0; n8 < 8; ++n8) {
          bf16x8 vf = *(const bf16x8*)&Vs[buf][(g * 128 + n8 * 16 + l15) * 8];
          o[n8] = mfma16(pf, vf, o[n8]);
        }
      }
      __syncthreads();  // all waves done with buf before overwrite
      buf ^= 1;
    }

    float linv[4];
#pragma unroll
    for (int r = 0; r < 4; ++r) linv[r] = 1.0f / lrow[r];
#pragma unroll
    for (int n8 = 0; n8 < 8; ++n8) {
#pragma unroll
      for (int r = 0; r < 4; ++r) {
        const int q = q0 + 4 * g + r;
        O[((size_t)(b * TT + q)) * (NH * HDIM) + h * HDIM + n8 * 16 + l15] =
            f2bf(o[n8][r] * linv[r]);
      }
    }
  }
}

// ---------------------------------------------------------------------- launch
extern "C" void kernel_launch(void* const* d_in, const int* in_sizes, int n_in,
                              void* d_out, int out_size, void* d_ws, size_t ws_size,
                              hipStream_t stream) {
  const float* x  = (const float*)d_in[0];
  const float* Wq = (const float*)d_in[1];
  const float* Wk = (const float*)d_in[2];
  const float* Wv = (const float*)d_in[3];
  const float* Wo = (const float*)d_in[4];
  float* out = (float*)d_out;

  char* ws = (char*)d_ws;
  size_t off = 0;
  unsigned short* xb  = (unsigned short*)(ws + off); off += (size_t)MSZ * DD * 2;   // 32 MiB (reused as O)
  unsigned short* Wtq = (unsigned short*)(ws + off); off += (size_t)NQKV * DD * 2;  // 24 MiB
  unsigned short* Wto = (unsigned short*)(ws + off); off += (size_t)DD * DD * 2;    // 8 MiB
  unsigned short* Qb  = (unsigned short*)(ws + off); off += (size_t)MSZ * DD * 2;   // 32 MiB
  unsigned short* Kb  = (unsigned short*)(ws + off); off += (size_t)MSZ * DD * 2;   // 32 MiB
  unsigned short* Vt  = (unsigned short*)(ws + off); off += (size_t)MSZ * DD * 2;   // 32 MiB
  unsigned short* Ob  = xb;  // x_bf16 dead after QKV GEMM -> reuse for attn out

  cvtx<<<2048, 256, 0, stream>>>(x, xb);
  transW<<<dim3(64, 64, 4), 256, 0, stream>>>(Wq, Wk, Wv, Wo, Wtq, Wto);
  gemm8<0><<<dim3(NQKV / 256, MSZ / 256), 512, 0, stream>>>(xb, Wtq, Qb, Kb, Vt, nullptr);
  attn<<<dim3(16, NB * NH), 256, 0, stream>>>(Qb, Kb, Vt, Ob);
  gemm8<1><<<dim3(DD / 256, MSZ / 256), 512, 0, stream>>>(Ob, Wto, nullptr, nullptr, nullptr, out);
}

// Round 5
// 574.801 us; speedup vs baseline: 2.4856x; 1.0910x over previous
//
#include <hip/hip_runtime.h>
#include <hip/hip_bf16.h>
#include <stdint.h>

// Problem: B=4, T=2048, D=2048, H=16, HD=128.  out = Attn(xWq, xWk, xWv) Wo
#define TT   2048
#define DD   2048
#define NH   16
#define NB   4
#define HDIM 128
#define MSZ  (NB * TT)      // 8192 rows for the token-major GEMMs
#define NQKV (3 * DD)       // 6144 fused QKV output columns
#define NT   32             // K tiles of 64: 2048/64

typedef __attribute__((ext_vector_type(8))) __bf16 bf16x8;
typedef __attribute__((ext_vector_type(4))) float  f32x4;

typedef __attribute__((address_space(3))) void       lds_void;
typedef const __attribute__((address_space(1))) void g_void;

__device__ inline unsigned short f2bf(float f) {
  union { float f; unsigned u; } v; v.f = f;
  unsigned r = v.u + 0x7fffu + ((v.u >> 16) & 1u);  // round-to-nearest-even
  return (unsigned short)(r >> 16);
}

__device__ inline unsigned short bfc(float f) {  // compiler-lowered cvt
  return __builtin_bit_cast(unsigned short, (__bf16)f);
}

__device__ inline void gload16(const void* g, void* l) {
  __builtin_amdgcn_global_load_lds((g_void*)g, (lds_void*)l, 16, 0, 0);
}

__device__ inline f32x4 mfma16(bf16x8 a, bf16x8 b, f32x4 c) {
  return __builtin_amdgcn_mfma_f32_16x16x32_bf16(a, b, c, 0, 0, 0);
}

// 16-lane max-reduce step via DPP row_ror (VALU pipe; all lanes active).
#define RORMAX(x, C)                                                        \
  do {                                                                      \
    int pi_ = __builtin_amdgcn_mov_dpp(__builtin_bit_cast(int, x), (C),     \
                                       0xF, 0xF, true);                     \
    x = fmaxf(x, __builtin_bit_cast(float, pi_));                           \
  } while (0)

// ---------------------------------------------------------------- cvt x->bf16
__global__ __launch_bounds__(256) void cvtx(const float* __restrict__ x,
                                            unsigned short* __restrict__ xb) {
  const int n4 = MSZ * DD / 4;
  for (int i = blockIdx.x * blockDim.x + threadIdx.x; i < n4;
       i += gridDim.x * blockDim.x) {
    float4 v = ((const float4*)x)[i];
    uint2 u;
    u.x = (unsigned)f2bf(v.x) | ((unsigned)f2bf(v.y) << 16);
    u.y = (unsigned)f2bf(v.z) | ((unsigned)f2bf(v.w) << 16);
    *(uint2*)&xb[(size_t)i * 4] = u;
  }
}

// ------------------------------------------- W (K,N) f32 -> Wt (N,K) bf16
__global__ __launch_bounds__(256) void transW(const float* __restrict__ Wq,
                                              const float* __restrict__ Wk,
                                              const float* __restrict__ Wv,
                                              const float* __restrict__ Wo,
                                              unsigned short* __restrict__ Wtq,
                                              unsigned short* __restrict__ Wto) {
  __shared__ float tl[32][33];
  const int z = blockIdx.z;
  const float* W = (z == 0) ? Wq : (z == 1) ? Wk : (z == 2) ? Wv : Wo;
  unsigned short* outp = (z < 3) ? (Wtq + (size_t)z * DD * DD) : Wto;
  const int c = threadIdx.x & 31, r8 = threadIdx.x >> 5;
  const int k0 = blockIdx.y * 32, n0 = blockIdx.x * 32;
#pragma unroll
  for (int i = 0; i < 4; ++i)
    tl[r8 + 8 * i][c] = W[(size_t)(k0 + r8 + 8 * i) * DD + n0 + c];
  __syncthreads();
#pragma unroll
  for (int i = 0; i < 4; ++i)
    outp[(size_t)(n0 + r8 + 8 * i) * DD + k0 + c] = f2bf(tl[c][r8 + 8 * i]);
}

// ------------------------------------------------- 256x256 8-phase GEMM (B^T)
// C[M,N] = A[M,K] * Bt[N,K]^T, K = 2048.  512 thr = 8 waves (2M x 4N), each
// wave owns 128x64 of C.  BK=64; LDS = 2 dbuf x 2 half x 128x64 x {A,B} x 2B
// = 128 KiB.  Half layout: [ch(2)][row(128)][col(32)] bf16, phys byte =
// logical ^ ((bit9)<<5) (st_16x32 swizzle; linear gload dest + pre-swizzled
// global src + swizzled ds_read).  Per tile: 4 phases x {stage 1 half,
// barrier, 16 MFMA, barrier}; all 24 frag ds_reads in phase 0 (pinned by
// lgkmcnt(0) asm); vmcnt(6) once per tile (3 half-tiles in flight).
template <int EPI>
__global__ __launch_bounds__(512, 2) void gemm8(
    const unsigned short* __restrict__ A, const unsigned short* __restrict__ Bt,
    unsigned short* __restrict__ Qb, unsigned short* __restrict__ Kb,
    unsigned short* __restrict__ Vt, float* __restrict__ Cf) {
  __shared__ __align__(16) unsigned short As[2][2][8192];
  __shared__ __align__(16) unsigned short Bs[2][2][8192];
  const int tid = threadIdx.x;
  const int lane = tid & 63;
  const int w = tid >> 6;
  const int wm = w >> 2, wn = w & 3;
  const int l15 = lane & 15, g = lane >> 4;
  const int m0 = blockIdx.y * 256, n0 = blockIdx.x * 256;

  // staging: thread writes linear LDS bytes [tid*16 .. +16) (+8KiB for j=1);
  // content there must be logical offset u = swz(dest).
  const int u  = (tid * 16) ^ (((tid >> 5) & 1) << 5);
  const int sr = (u >> 6) & 127;     // row within half
  const int sc = (u & 63) >> 1;      // col within 32-chunk
  const unsigned short* sA0 = A  + (size_t)(m0 + sr) * DD + sc;
  const unsigned short* sA1 = A  + (size_t)(m0 + 128 + sr) * DD + sc;
  const unsigned short* sB0 = Bt + (size_t)(n0 + sr) * DD + sc;
  const unsigned short* sB1 = Bt + (size_t)(n0 + 128 + sr) * DD + sc;

  // frag read base (ushort idx): swizzle bit depends only on l15 bit3.
  const int pA = ((l15 * 64 + g * 16) ^ (((l15 >> 3) & 1) << 5)) >> 1;
  const int pB = (wn & 1) * 2048 + pA;

  f32x4 acc[8][4] = {};

#define STAGE(kt, hf)                                                         \
  do {                                                                        \
    if ((kt) < NT) {                                                          \
      const unsigned short* s_ = (hf) == 0 ? sA0 : (hf) == 1 ? sA1            \
                                 : (hf) == 2 ? sB0 : sB1;                     \
      s_ += (kt) * 64;                                                        \
      unsigned short* d_ = ((hf) < 2 ? &As[(kt) & 1][(hf) & 1][0]             \
                                     : &Bs[(kt) & 1][(hf) & 1][0]) + tid * 8; \
      gload16(s_, d_);                                                        \
      gload16(s_ + 32, d_ + 4096);                                            \
    }                                                                         \
  } while (0)

#define MFMAQ(q)                                                              \
  do {                                                                        \
    __builtin_amdgcn_s_setprio(1);                                            \
    _Pragma("unroll") for (int n2 = 0; n2 < 2; ++n2)                          \
    _Pragma("unroll") for (int m2 = 0; m2 < 4; ++m2)                          \
    _Pragma("unroll") for (int kk = 0; kk < 2; ++kk)                          \
      acc[((q) & 1) * 4 + m2][((q) >> 1) * 2 + n2] =                          \
          mfma16(af[((q) & 1) * 4 + m2][kk], bq[((q) >> 1) * 2 + n2][kk],     \
                 acc[((q) & 1) * 4 + m2][((q) >> 1) * 2 + n2]);               \
    __builtin_amdgcn_s_setprio(0);                                            \
  } while (0)

#define TILE(t, buf)                                                          \
  do {                                                                        \
    const unsigned short* Ab = &As[buf][wm][0];                               \
    const unsigned short* Bb = &Bs[buf][wn >> 1][0];                          \
    bf16x8 af[8][2], bq[4][2];                                                \
    _Pragma("unroll") for (int m = 0; m < 8; ++m) {                           \
      af[m][0] = *(const bf16x8*)&Ab[pA + m * 512];                           \
      af[m][1] = *(const bf16x8*)&Ab[pA + m * 512 + 4096];                    \
    }                                                                         \
    _Pragma("unroll") for (int n = 0; n < 4; ++n) {                           \
      bq[n][0] = *(const bf16x8*)&Bb[pB + n * 512];                           \
      bq[n][1] = *(const bf16x8*)&Bb[pB + n * 512 + 4096];                    \
    }                                                                         \
    STAGE((t) + 1, 3);                                                        \
    __builtin_amdgcn_s_barrier();                                             \
    MFMAQ(0);                                                                 \
    asm volatile("s_waitcnt lgkmcnt(0)" ::: "memory");                        \
    __builtin_amdgcn_sched_barrier(0);                                        \
    __builtin_amdgcn_s_barrier();                                             \
    STAGE((t) + 2, 0);                                                        \
    __builtin_amdgcn_s_barrier();                                             \
    MFMAQ(1);                                                                 \
    __builtin_amdgcn_s_barrier();                                             \
    STAGE((t) + 2, 1);                                                        \
    __builtin_amdgcn_s_barrier();                                             \
    MFMAQ(2);                                                                 \
    __builtin_amdgcn_s_barrier();                                             \
    STAGE((t) + 2, 2);                                                        \
    __builtin_amdgcn_s_barrier();                                             \
    MFMAQ(3);                                                                 \
    asm volatile("s_waitcnt vmcnt(6)" ::: "memory");                          \
    __builtin_amdgcn_sched_barrier(0);                                        \
    __builtin_amdgcn_s_barrier();                                             \
  } while (0)

  // prologue: tile0 fully + tile1 halves 0-2 (h3 staged at P(0,0)).
  STAGE(0, 0); STAGE(0, 1); STAGE(0, 2); STAGE(0, 3);
  STAGE(1, 0); STAGE(1, 1); STAGE(1, 2);
  asm volatile("s_waitcnt vmcnt(6)" ::: "memory");
  __builtin_amdgcn_sched_barrier(0);
  __builtin_amdgcn_s_barrier();

#pragma unroll 1
  for (int it = 0; it < NT / 2; ++it) {
    TILE(2 * it, 0);
    TILE(2 * it + 1, 1);
  }
#undef TILE
#undef MFMAQ
#undef STAGE

  // Epilogue. C frag: row = 4*g + r, col = l15 (m89-verified mapping).
  // Q is pre-scaled by log2(e)/sqrt(HD) so attention runs in exp2 domain.
  const float QSCALE = 0.1275174308f;
#pragma unroll
  for (int m = 0; m < 8; ++m) {
#pragma unroll
    for (int n = 0; n < 4; ++n) {
      const int row0 = m0 + wm * 128 + m * 16 + 4 * g;
      const int col2 = wn * 64 + n * 16;
      const int col = n0 + col2 + l15;
      if (EPI == 1) {
#pragma unroll
        for (int r = 0; r < 4; ++r)
          Cf[(size_t)(row0 + r) * DD + col] = acc[m][n][r];
      } else {
        const int mat = n0 >> 11;                    // uniform per block
        const int h = ((n0 & 2047) + col2) >> 7;     // uniform per (wave,n)
        const int hd = (col2 & 127) + l15;
        if (mat == 0) {
#pragma unroll
          for (int r = 0; r < 4; ++r) {
            const int mm = row0 + r, b = mm >> 11, t = mm & 2047;
            Qb[((size_t)(b * NH + h) * TT + t) * HDIM + hd] =
                f2bf(acc[m][n][r] * QSCALE);
          }
        } else if (mat == 1) {
#pragma unroll
          for (int r = 0; r < 4; ++r) {
            const int mm = row0 + r, b = mm >> 11, t = mm & 2047;
            Kb[((size_t)(b * NH + h) * TT + t) * HDIM + hd] = f2bf(acc[m][n][r]);
          }
        } else {  // V stored transposed: Vt[b,h,hd,t]
          const int b = row0 >> 11, t = row0 & 2047;  // 4 rows share b
          uint2 uu;
          uu.x = (unsigned)f2bf(acc[m][n][0]) | ((unsigned)f2bf(acc[m][n][1]) << 16);
          uu.y = (unsigned)f2bf(acc[m][n][2]) | ((unsigned)f2bf(acc[m][n][3]) << 16);
          *(uint2*)&Vt[((size_t)(b * NH + h) * HDIM + hd) * TT + t] = uu;
        }
      }
    }
  }
}

// ------------------------------------------------------------ flash attention
// 1D grid 1024 = (16 bx) x (64 bh), XCD-clustered: all 16 bx of one bh land
// on one XCD (bid%8 == XCD) for K/V L2 reuse.  256 thr = 4 waves.  Block bx
// processes q-tiles {31-bx, bx} (causal pairing -> uniform 66 kv-tiles).
// K/V double-buffered in LDS via global_load_lds.  Q pre-scaled by
// log2e/sqrt(HD) -> exp2 softmax; defer-max (THR=12 log2); row max via DPP
// ror; row sum via one extra MFMA with all-ones B (P @ 1).
__global__ __launch_bounds__(256, 4) void attn(const unsigned short* __restrict__ Qb,
                                               const unsigned short* __restrict__ Kb,
                                               const unsigned short* __restrict__ Vt,
                                               unsigned short* __restrict__ O) {
  // K tile: 32 kv-rows x 128 hd.  16B unit index = ch*32 + row, ch = hd-chunk.
  // V tile: 128 hd-rows x 32 kv.  16B unit index = c*128 + row, c = kv-chunk.
  __shared__ __align__(16) unsigned short Ks[2][4096];
  __shared__ __align__(16) unsigned short Vs[2][4096];
  __shared__ __align__(16) unsigned short pl[4][16][40];  // P bounce, pad 40

  const int bid = blockIdx.x;
  const int bx = (bid >> 3) & 15;            // 0..15
  const int bh = (bid & 7) + 8 * (bid >> 7); // 0..63, XCD-clustered
  const int tid = threadIdx.x;
  const int w = tid >> 6;
  const int lane = tid & 63;
  const int l15 = lane & 15, g = lane >> 4;

  const unsigned short* Qh = Qb + (size_t)bh * TT * HDIM;
  const unsigned short* Kh = Kb + (size_t)bh * TT * HDIM;
  const unsigned short* Vh = Vt + (size_t)bh * HDIM * TT;
  const int b = bh >> 4, h = bh & 15;

  bf16x8 ones;
#pragma unroll
  for (int i = 0; i < 8; ++i) ones[i] = (__bf16)1.0f;

  // staging constants: thread -> 16B unit == tid (round 0) / tid+256 (round 1)
  const int kch = tid >> 5, krow = tid & 31;    // K: unit = ch*32+row
  const int vc = tid >> 7, vrow = tid & 127;    // V: unit = c*128+row

  int buf = 0;
#pragma unroll 1
  for (int ph = 0; ph < 2; ++ph) {
    const int qt = ph ? bx : (31 - bx);
    const int q0 = qt * 64 + w * 16;
    const int nt = 2 * qt + 2;

    bf16x8 qf[4];
#pragma unroll
    for (int kc = 0; kc < 4; ++kc)
      qf[kc] = *(const bf16x8*)&Qh[(size_t)(q0 + l15) * HDIM + kc * 32 + g * 8];

    f32x4 o[8] = {};
    float mrow[4], lrow[4];
#pragma unroll
    for (int r = 0; r < 4; ++r) { mrow[r] = -1e30f; lrow[r] = 0.f; }

    // prologue: stage tile 0
    {
      const int kv0 = 0;
      gload16(Kh + (size_t)(kv0 + krow) * HDIM + kch * 8,      &Ks[buf][(kch * 32 + krow) * 8]);
      gload16(Kh + (size_t)(kv0 + krow) * HDIM + (kch + 8) * 8,&Ks[buf][((kch + 8) * 32 + krow) * 8]);
      gload16(Vh + (size_t)vrow * TT + kv0 + vc * 8,           &Vs[buf][(vc * 128 + vrow) * 8]);
      gload16(Vh + (size_t)vrow * TT + kv0 + (vc + 2) * 8,     &Vs[buf][((vc + 2) * 128 + vrow) * 8]);
    }

#pragma unroll 1
    for (int t = 0; t < nt; ++t) {
      const int kv0 = t * 32;
      __syncthreads();  // vmcnt drained -> tile t resident in buf
      if (t + 1 < nt) {
        const int kvn = kv0 + 32;
        gload16(Kh + (size_t)(kvn + krow) * HDIM + kch * 8,      &Ks[buf ^ 1][(kch * 32 + krow) * 8]);
        gload16(Kh + (size_t)(kvn + krow) * HDIM + (kch + 8) * 8,&Ks[buf ^ 1][((kch + 8) * 32 + krow) * 8]);
        gload16(Vh + (size_t)vrow * TT + kvn + vc * 8,           &Vs[buf ^ 1][(vc * 128 + vrow) * 8]);
        gload16(Vh + (size_t)vrow * TT + kvn + (vc + 2) * 8,     &Vs[buf ^ 1][((vc + 2) * 128 + vrow) * 8]);
      }

      if (kv0 <= q0 + 15) {  // skip fully-masked tiles (barriers still honored)
        f32x4 s0 = {}, s1 = {};
#pragma unroll
        for (int kc = 0; kc < 4; ++kc) {
          bf16x8 k0 = *(const bf16x8*)&Ks[buf][((kc * 4 + g) * 32 + l15) * 8];
          bf16x8 k1 = *(const bf16x8*)&Ks[buf][((kc * 4 + g) * 32 + 16 + l15) * 8];
          s0 = mfma16(qf[kc], k0, s0);
          s1 = mfma16(qf[kc], k1, s1);
        }
        // causal mask: element (q = q0+4g+r, kv = kv0 + {0,16} + l15)
        float pmax[4];
#pragma unroll
        for (int r = 0; r < 4; ++r) {
          const int q = q0 + 4 * g + r;
          if (kv0 + l15 > q) s0[r] = -1e30f;
          if (kv0 + 16 + l15 > q) s1[r] = -1e30f;
          pmax[r] = fmaxf(s0[r], s1[r]);
        }
#pragma unroll
        for (int r = 0; r < 4; ++r) {  // 16-lane row max on VALU (DPP ror)
          RORMAX(pmax[r], 0x121);
          RORMAX(pmax[r], 0x122);
          RORMAX(pmax[r], 0x124);
          RORMAX(pmax[r], 0x128);
        }
        int need = 0;
#pragma unroll
        for (int r = 0; r < 4; ++r) need |= (pmax[r] > mrow[r] + 12.0f);
        if (__any(need)) {  // wave-uniform rescale (rare after warmup)
          float al[4];
#pragma unroll
          for (int r = 0; r < 4; ++r) {
            const float mn = fmaxf(mrow[r], pmax[r]);
            al[r] = __builtin_amdgcn_exp2f(mrow[r] - mn);
            mrow[r] = mn;
            lrow[r] *= al[r];
          }
#pragma unroll
          for (int n8 = 0; n8 < 8; ++n8)
#pragma unroll
            for (int r = 0; r < 4; ++r) o[n8][r] *= al[r];
        }
#pragma unroll
        for (int r = 0; r < 4; ++r) {
          s0[r] = __builtin_amdgcn_exp2f(s0[r] - mrow[r]);
          s1[r] = __builtin_amdgcn_exp2f(s1[r] - mrow[r]);
        }

        // P (f32, C-layout) -> wave-private LDS -> bf16 A-frag
#pragma unroll
        for (int r = 0; r < 4; ++r) {
          pl[w][4 * g + r][l15] = bfc(s0[r]);
          pl[w][4 * g + r][16 + l15] = bfc(s1[r]);
        }
        bf16x8 pf = *(const bf16x8*)&pl[w][l15][g * 8];  // compiler emits lgkmcnt
        f32x4 z = {};
        f32x4 sm = mfma16(pf, ones, z);  // row-sum of P (replaces shfl tree)
#pragma unroll
        for (int r = 0; r < 4; ++r) lrow[r] += sm[r];
#pragma unroll
        for (int n8 = 0; n8 < 8; ++n8) {
          bf16x8 vf = *(const bf16x8*)&Vs[buf][(g * 128 + n8 * 16 + l15) * 8];
          o[n8] = mfma16(pf, vf, o[n8]);
        }
      }
      __syncthreads();  // all waves done with buf before overwrite
      buf ^= 1;
    }

    float linv[4];
#pragma unroll
    for (int r = 0; r < 4; ++r) linv[r] = 1.0f / lrow[r];
#pragma unroll
    for (int n8 = 0; n8 < 8; ++n8) {
#pragma unroll
      for (int r = 0; r < 4; ++r) {
        const int q = q0 + 4 * g + r;
        O[((size_t)(b * TT + q)) * (NH * HDIM) + h * HDIM + n8 * 16 + l15] =
            f2bf(o[n8][r] * linv[r]);
      }
    }
  }
}

// ---------------------------------------------------------------------- launch
extern "C" void kernel_launch(void* const* d_in, const int* in_sizes, int n_in,
                              void* d_out, int out_size, void* d_ws, size_t ws_size,
                              hipStream_t stream) {
  const float* x  = (const float*)d_in[0];
  const float* Wq = (const float*)d_in[1];
  const float* Wk = (const float*)d_in[2];
  const float* Wv = (const float*)d_in[3];
  const float* Wo = (const float*)d_in[4];
  float* out = (float*)d_out;

  char* ws = (char*)d_ws;
  size_t off = 0;
  unsigned short* xb  = (unsigned short*)(ws + off); off += (size_t)MSZ * DD * 2;   // 32 MiB (reused as O)
  unsigned short* Wtq = (unsigned short*)(ws + off); off += (size_t)NQKV * DD * 2;  // 24 MiB
  unsigned short* Wto = (unsigned short*)(ws + off); off += (size_t)DD * DD * 2;    // 8 MiB
  unsigned short* Qb  = (unsigned short*)(ws + off); off += (size_t)MSZ * DD * 2;   // 32 MiB
  unsigned short* Kb  = (unsigned short*)(ws + off); off += (size_t)MSZ * DD * 2;   // 32 MiB
  unsigned short* Vt  = (unsigned short*)(ws + off); off += (size_t)MSZ * DD * 2;   // 32 MiB
  unsigned short* Ob  = xb;  // x_bf16 dead after QKV GEMM -> reuse for attn out

  cvtx<<<2048, 256, 0, stream>>>(x, xb);
  transW<<<dim3(64, 64, 4), 256, 0, stream>>>(Wq, Wk, Wv, Wo, Wtq, Wto);
  gemm8<0><<<dim3(NQKV / 256, MSZ / 256), 512, 0, stream>>>(xb, Wtq, Qb, Kb, Vt, nullptr);
  attn<<<1024, 256, 0, stream>>>(Qb, Kb, Vt, Ob);
  gemm8<1><<<dim3(DD / 256, MSZ / 256), 512, 0, stream>>>(Ob, Wto, nullptr, nullptr, nullptr, out);
}

// Round 7
// 558.708 us; speedup vs baseline: 2.5572x; 1.0288x over previous
//
#include <hip/hip_runtime.h>
#include <hip/hip_bf16.h>
#include <stdint.h>

// Problem: B=4, T=2048, D=2048, H=16, HD=128.  out = Attn(xWq, xWk, xWv) Wo
#define TT   2048
#define DD   2048
#define NH   16
#define NB   4
#define HDIM 128
#define MSZ  (NB * TT)      // 8192 rows for the token-major GEMMs
#define NQKV (3 * DD)       // 6144 fused QKV output columns
#define NT   32             // K tiles of 64: 2048/64

typedef __attribute__((ext_vector_type(8))) __bf16 bf16x8;
typedef __attribute__((ext_vector_type(4))) float  f32x4;

typedef __attribute__((address_space(3))) void       lds_void;
typedef const __attribute__((address_space(1))) void g_void;

__device__ inline unsigned short f2bf(float f) {
  union { float f; unsigned u; } v; v.f = f;
  unsigned r = v.u + 0x7fffu + ((v.u >> 16) & 1u);  // round-to-nearest-even
  return (unsigned short)(r >> 16);
}

__device__ inline unsigned short bfc(float f) {  // compiler-lowered cvt
  return __builtin_bit_cast(unsigned short, (__bf16)f);
}

__device__ inline void gload16(const void* g, void* l) {
  __builtin_amdgcn_global_load_lds((g_void*)g, (lds_void*)l, 16, 0, 0);
}

__device__ inline f32x4 mfma16(bf16x8 a, bf16x8 b, f32x4 c) {
  return __builtin_amdgcn_mfma_f32_16x16x32_bf16(a, b, c, 0, 0, 0);
}

// 16-lane max-reduce step via DPP row_ror (VALU pipe; all lanes active).
#define RORMAX(x, C)                                                        \
  do {                                                                      \
    int pi_ = __builtin_amdgcn_mov_dpp(__builtin_bit_cast(int, x), (C),     \
                                       0xF, 0xF, true);                     \
    x = fmaxf(x, __builtin_bit_cast(float, pi_));                           \
  } while (0)

// ---------------------------------------------------------------- cvt x->bf16
__global__ __launch_bounds__(256) void cvtx(const float* __restrict__ x,
                                            unsigned short* __restrict__ xb) {
  const int n4 = MSZ * DD / 4;
  for (int i = blockIdx.x * blockDim.x + threadIdx.x; i < n4;
       i += gridDim.x * blockDim.x) {
    float4 v = ((const float4*)x)[i];
    uint2 u;
    u.x = (unsigned)f2bf(v.x) | ((unsigned)f2bf(v.y) << 16);
    u.y = (unsigned)f2bf(v.z) | ((unsigned)f2bf(v.w) << 16);
    *(uint2*)&xb[(size_t)i * 4] = u;
  }
}

// ------------------------------------------- W (K,N) f32 -> Wt (N,K) bf16
__global__ __launch_bounds__(256) void transW(const float* __restrict__ Wq,
                                              const float* __restrict__ Wk,
                                              const float* __restrict__ Wv,
                                              const float* __restrict__ Wo,
                                              unsigned short* __restrict__ Wtq,
                                              unsigned short* __restrict__ Wto) {
  __shared__ float tl[32][33];
  const int z = blockIdx.z;
  const float* W = (z == 0) ? Wq : (z == 1) ? Wk : (z == 2) ? Wv : Wo;
  unsigned short* outp = (z < 3) ? (Wtq + (size_t)z * DD * DD) : Wto;
  const int c = threadIdx.x & 31, r8 = threadIdx.x >> 5;
  const int k0 = blockIdx.y * 32, n0 = blockIdx.x * 32;
#pragma unroll
  for (int i = 0; i < 4; ++i)
    tl[r8 + 8 * i][c] = W[(size_t)(k0 + r8 + 8 * i) * DD + n0 + c];
  __syncthreads();
#pragma unroll
  for (int i = 0; i < 4; ++i)
    outp[(size_t)(n0 + r8 + 8 * i) * DD + k0 + c] = f2bf(tl[c][r8 + 8 * i]);
}

// ------------------------------------------------- 256x256 8-phase GEMM (B^T)
// C[M,N] = A[M,K] * Bt[N,K]^T, K = 2048.  512 thr = 8 waves (2M x 4N), each
// wave owns 128x64 of C.  BK=64; LDS = 128 KiB.  st_16x32 swizzle (linear
// gload dest + pre-swizzled global src + swizzled ds_read).  Frag reads split
// 12+12 (batch1 overlaps MFMAQ(0)); kk-outer MFMA order (dep-pairs spaced);
// vmcnt(6) once per tile, vmcnt(0) at the last two tiles (tail drain).
// Grid is 1D, XCD-swizzled: chunk of nwg/8 consecutive tiles per XCD.
template <int EPI, int GX>
__global__ __launch_bounds__(512, 2) void gemm8(
    const unsigned short* __restrict__ A, const unsigned short* __restrict__ Bt,
    unsigned short* __restrict__ Qb, unsigned short* __restrict__ Kb,
    unsigned short* __restrict__ Vt, float* __restrict__ Cf) {
  __shared__ __align__(16) unsigned short As[2][2][8192];
  __shared__ __align__(16) unsigned short Bs[2][2][8192];
  const int tid = threadIdx.x;
  const int lane = tid & 63;
  const int w = tid >> 6;
  const int wm = w >> 2, wn = w & 3;
  const int l15 = lane & 15, g = lane >> 4;
  const int bid = blockIdx.x;
  const int swz = (bid & 7) * (GX * 4) + (bid >> 3);  // nwg = GX*32, %8==0
  const int m0 = (swz / GX) * 256, n0 = (swz % GX) * 256;

  // staging: thread writes linear LDS bytes [tid*16 .. +16) (+8KiB for j=1);
  // content there must be logical offset u = swz(dest).
  const int u  = (tid * 16) ^ (((tid >> 5) & 1) << 5);
  const int sr = (u >> 6) & 127;     // row within half
  const int sc = (u & 63) >> 1;      // col within 32-chunk
  const unsigned short* sA0 = A  + (size_t)(m0 + sr) * DD + sc;
  const unsigned short* sA1 = A  + (size_t)(m0 + 128 + sr) * DD + sc;
  const unsigned short* sB0 = Bt + (size_t)(n0 + sr) * DD + sc;
  const unsigned short* sB1 = Bt + (size_t)(n0 + 128 + sr) * DD + sc;

  // frag read base (ushort idx): swizzle bit depends only on l15 bit3.
  const int pA = ((l15 * 64 + g * 16) ^ (((l15 >> 3) & 1) << 5)) >> 1;
  const int pB = (wn & 1) * 2048 + pA;

  f32x4 acc[8][4] = {};

#define STAGE(kt, hf)                                                         \
  do {                                                                        \
    if ((kt) < NT) {                                                          \
      const unsigned short* s_ = (hf) == 0 ? sA0 : (hf) == 1 ? sA1            \
                                 : (hf) == 2 ? sB0 : sB1;                     \
      s_ += (kt) * 64;                                                        \
      unsigned short* d_ = ((hf) < 2 ? &As[(kt) & 1][(hf) & 1][0]             \
                                     : &Bs[(kt) & 1][(hf) & 1][0]) + tid * 8; \
      gload16(s_, d_);                                                        \
      gload16(s_ + 32, d_ + 4096);                                            \
    }                                                                         \
  } while (0)

#define LDA(m)                                                                \
  do {                                                                        \
    af[m][0] = *(const bf16x8*)&Ab[pA + (m) * 512];                           \
    af[m][1] = *(const bf16x8*)&Ab[pA + (m) * 512 + 4096];                    \
  } while (0)
#define LDB(n)                                                                \
  do {                                                                        \
    bq[n][0] = *(const bf16x8*)&Bb[pB + (n) * 512];                           \
    bq[n][1] = *(const bf16x8*)&Bb[pB + (n) * 512 + 4096];                    \
  } while (0)

// kk OUTER: 8 independent MFMAs between the dependent kk=0/kk=1 acc pairs.
#define MFMAQ(q)                                                              \
  do {                                                                        \
    __builtin_amdgcn_s_setprio(1);                                            \
    _Pragma("unroll") for (int kk = 0; kk < 2; ++kk)                          \
    _Pragma("unroll") for (int n2 = 0; n2 < 2; ++n2)                          \
    _Pragma("unroll") for (int m2 = 0; m2 < 4; ++m2)                          \
      acc[((q) & 1) * 4 + m2][((q) >> 1) * 2 + n2] =                          \
          mfma16(af[((q) & 1) * 4 + m2][kk], bq[((q) >> 1) * 2 + n2][kk],     \
                 acc[((q) & 1) * 4 + m2][((q) >> 1) * 2 + n2]);               \
    __builtin_amdgcn_s_setprio(0);                                            \
  } while (0)

#define TILE(t, buf, VM)                                                      \
  do {                                                                        \
    const unsigned short* Ab = &As[buf][wm][0];                               \
    const unsigned short* Bb = &Bs[buf][wn >> 1][0];                          \
    bf16x8 af[8][2], bq[4][2];                                                \
    LDA(0); LDA(1); LDA(2); LDA(3);                                           \
    LDB(0); LDB(1);                                                           \
    STAGE((t) + 1, 3);                                                        \
    __builtin_amdgcn_s_barrier();                                             \
    MFMAQ(0); /* compiler auto-waits batch-0 lgkm deps */                     \
    LDA(4); LDA(5); LDA(6); LDA(7);                                           \
    LDB(2); LDB(3);                                                           \
    asm volatile("s_waitcnt lgkmcnt(0)" ::: "memory");                        \
    __builtin_amdgcn_sched_barrier(0);                                        \
    __builtin_amdgcn_s_barrier(); /* all waves' reads done: buf reusable */   \
    STAGE((t) + 2, 0);                                                        \
    __builtin_amdgcn_s_barrier();                                             \
    MFMAQ(1);                                                                 \
    __builtin_amdgcn_s_barrier();                                             \
    STAGE((t) + 2, 1);                                                        \
    __builtin_amdgcn_s_barrier();                                             \
    MFMAQ(2);                                                                 \
    __builtin_amdgcn_s_barrier();                                             \
    STAGE((t) + 2, 2);                                                        \
    __builtin_amdgcn_s_barrier();                                             \
    MFMAQ(3);                                                                 \
    if (VM)                                                                   \
      asm volatile("s_waitcnt vmcnt(6)" ::: "memory");                        \
    else                                                                      \
      asm volatile("s_waitcnt vmcnt(0)" ::: "memory");                        \
    __builtin_amdgcn_sched_barrier(0);                                        \
    __builtin_amdgcn_s_barrier();                                             \
  } while (0)

  // prologue: tile0 fully + tile1 halves 0-2 (h3 staged during tile 0).
  STAGE(0, 0); STAGE(0, 1); STAGE(0, 2); STAGE(0, 3);
  STAGE(1, 0); STAGE(1, 1); STAGE(1, 2);
  asm volatile("s_waitcnt vmcnt(6)" ::: "memory");
  __builtin_amdgcn_sched_barrier(0);
  __builtin_amdgcn_s_barrier();

#pragma unroll 1
  for (int it = 0; it < NT / 2 - 1; ++it) {
    TILE(2 * it, 0, 6);
    TILE(2 * it + 1, 1, 6);
  }
  TILE(NT - 2, 0, 0);  // tail: only 8 loads outstanding -> full drain
  TILE(NT - 1, 1, 0);
#undef TILE
#undef MFMAQ
#undef LDB
#undef LDA
#undef STAGE

  // Epilogue. C frag: row = 4*g + r, col = l15 (m89-verified mapping).
  // Q is pre-scaled by log2(e)/sqrt(HD) so attention runs in exp2 domain.
  const float QSCALE = 0.1275174308f;
#pragma unroll
  for (int m = 0; m < 8; ++m) {
#pragma unroll
    for (int n = 0; n < 4; ++n) {
      const int row0 = m0 + wm * 128 + m * 16 + 4 * g;
      const int col2 = wn * 64 + n * 16;
      const int col = n0 + col2 + l15;
      if (EPI == 1) {
#pragma unroll
        for (int r = 0; r < 4; ++r)
          Cf[(size_t)(row0 + r) * DD + col] = acc[m][n][r];
      } else {
        const int mat = n0 >> 11;                    // uniform per block
        const int h = ((n0 & 2047) + col2) >> 7;     // uniform per (wave,n)
        const int hd = (col2 & 127) + l15;
        if (mat == 0) {
#pragma unroll
          for (int r = 0; r < 4; ++r) {
            const int mm = row0 + r, b = mm >> 11, t = mm & 2047;
            Qb[((size_t)(b * NH + h) * TT + t) * HDIM + hd] =
                f2bf(acc[m][n][r] * QSCALE);
          }
        } else if (mat == 1) {
#pragma unroll
          for (int r = 0; r < 4; ++r) {
            const int mm = row0 + r, b = mm >> 11, t = mm & 2047;
            Kb[((size_t)(b * NH + h) * TT + t) * HDIM + hd] = f2bf(acc[m][n][r]);
          }
        } else {  // V stored transposed: Vt[b,h,hd,t]
          const int b = row0 >> 11, t = row0 & 2047;  // 4 rows share b
          uint2 uu;
          uu.x = (unsigned)f2bf(acc[m][n][0]) | ((unsigned)f2bf(acc[m][n][1]) << 16);
          uu.y = (unsigned)f2bf(acc[m][n][2]) | ((unsigned)f2bf(acc[m][n][3]) << 16);
          *(uint2*)&Vt[((size_t)(b * NH + h) * HDIM + hd) * TT + t] = uu;
        }
      }
    }
  }
}

// ------------------------------------------------------------ flash attention
// 1D grid 1024 = (16 bx) x (64 bh), XCD-clustered: all 16 bx of one bh land
// on one XCD (bid%8 == XCD) for K/V L2 reuse.  256 thr = 4 waves.  Block bx
// processes q-tiles {31-bx, bx} (causal pairing -> uniform 66 kv-tiles).
// K/V double-buffered in LDS via global_load_lds.  Q pre-scaled by
// log2e/sqrt(HD) -> exp2 softmax; defer-max (THR=12 log2); row max via DPP
// ror; row sum via one extra MFMA with all-ones B (P @ 1).
__global__ __launch_bounds__(256, 4) void attn(const unsigned short* __restrict__ Qb,
                                               const unsigned short* __restrict__ Kb,
                                               const unsigned short* __restrict__ Vt,
                                               unsigned short* __restrict__ O) {
  // K tile: 32 kv-rows x 128 hd.  16B unit index = ch*32 + row, ch = hd-chunk.
  // V tile: 128 hd-rows x 32 kv.  16B unit index = c*128 + row, c = kv-chunk.
  __shared__ __align__(16) unsigned short Ks[2][4096];
  __shared__ __align__(16) unsigned short Vs[2][4096];
  __shared__ __align__(16) unsigned short pl[4][16][40];  // P bounce, pad 40

  const int bid = blockIdx.x;
  const int bx = (bid >> 3) & 15;            // 0..15
  const int bh = (bid & 7) + 8 * (bid >> 7); // 0..63, XCD-clustered
  const int tid = threadIdx.x;
  const int w = tid >> 6;
  const int lane = tid & 63;
  const int l15 = lane & 15, g = lane >> 4;

  const unsigned short* Qh = Qb + (size_t)bh * TT * HDIM;
  const unsigned short* Kh = Kb + (size_t)bh * TT * HDIM;
  const unsigned short* Vh = Vt + (size_t)bh * HDIM * TT;
  const int b = bh >> 4, h = bh & 15;

  bf16x8 ones;
#pragma unroll
  for (int i = 0; i < 8; ++i) ones[i] = (__bf16)1.0f;

  // staging constants: thread -> 16B unit == tid (round 0) / tid+256 (round 1)
  const int kch = tid >> 5, krow = tid & 31;    // K: unit = ch*32+row
  const int vc = tid >> 7, vrow = tid & 127;    // V: unit = c*128+row

  int buf = 0;
#pragma unroll 1
  for (int ph = 0; ph < 2; ++ph) {
    const int qt = ph ? bx : (31 - bx);
    const int q0 = qt * 64 + w * 16;
    const int nt = 2 * qt + 2;

    bf16x8 qf[4];
#pragma unroll
    for (int kc = 0; kc < 4; ++kc)
      qf[kc] = *(const bf16x8*)&Qh[(size_t)(q0 + l15) * HDIM + kc * 32 + g * 8];

    f32x4 o[8] = {};
    float mrow[4], lrow[4];
#pragma unroll
    for (int r = 0; r < 4; ++r) { mrow[r] = -1e30f; lrow[r] = 0.f; }

    // prologue: stage tile 0
    {
      const int kv0 = 0;
      gload16(Kh + (size_t)(kv0 + krow) * HDIM + kch * 8,      &Ks[buf][(kch * 32 + krow) * 8]);
      gload16(Kh + (size_t)(kv0 + krow) * HDIM + (kch + 8) * 8,&Ks[buf][((kch + 8) * 32 + krow) * 8]);
      gload16(Vh + (size_t)vrow * TT + kv0 + vc * 8,           &Vs[buf][(vc * 128 + vrow) * 8]);
      gload16(Vh + (size_t)vrow * TT + kv0 + (vc + 2) * 8,     &Vs[buf][((vc + 2) * 128 + vrow) * 8]);
    }

#pragma unroll 1
    for (int t = 0; t < nt; ++t) {
      const int kv0 = t * 32;
      __syncthreads();  // vmcnt drained -> tile t resident in buf
      if (t + 1 < nt) {
        const int kvn = kv0 + 32;
        gload16(Kh + (size_t)(kvn + krow) * HDIM + kch * 8,      &Ks[buf ^ 1][(kch * 32 + krow) * 8]);
        gload16(Kh + (size_t)(kvn + krow) * HDIM + (kch + 8) * 8,&Ks[buf ^ 1][((kch + 8) * 32 + krow) * 8]);
        gload16(Vh + (size_t)vrow * TT + kvn + vc * 8,           &Vs[buf ^ 1][(vc * 128 + vrow) * 8]);
        gload16(Vh + (size_t)vrow * TT + kvn + (vc + 2) * 8,     &Vs[buf ^ 1][((vc + 2) * 128 + vrow) * 8]);
      }

      if (kv0 <= q0 + 15) {  // skip fully-masked tiles (barriers still honored)
        f32x4 s0 = {}, s1 = {};
#pragma unroll
        for (int kc = 0; kc < 4; ++kc) {
          bf16x8 k0 = *(const bf16x8*)&Ks[buf][((kc * 4 + g) * 32 + l15) * 8];
          bf16x8 k1 = *(const bf16x8*)&Ks[buf][((kc * 4 + g) * 32 + 16 + l15) * 8];
          s0 = mfma16(qf[kc], k0, s0);
          s1 = mfma16(qf[kc], k1, s1);
        }
        // causal mask: element (q = q0+4g+r, kv = kv0 + {0,16} + l15)
        float pmax[4];
#pragma unroll
        for (int r = 0; r < 4; ++r) {
          const int q = q0 + 4 * g + r;
          if (kv0 + l15 > q) s0[r] = -1e30f;
          if (kv0 + 16 + l15 > q) s1[r] = -1e30f;
          pmax[r] = fmaxf(s0[r], s1[r]);
        }
#pragma unroll
        for (int r = 0; r < 4; ++r) {  // 16-lane row max on VALU (DPP ror)
          RORMAX(pmax[r], 0x121);
          RORMAX(pmax[r], 0x122);
          RORMAX(pmax[r], 0x124);
          RORMAX(pmax[r], 0x128);
        }
        int need = 0;
#pragma unroll
        for (int r = 0; r < 4; ++r) need |= (pmax[r] > mrow[r] + 12.0f);
        if (__any(need)) {  // wave-uniform rescale (rare after warmup)
          float al[4];
#pragma unroll
          for (int r = 0; r < 4; ++r) {
            const float mn = fmaxf(mrow[r], pmax[r]);
            al[r] = __builtin_amdgcn_exp2f(mrow[r] - mn);
            mrow[r] = mn;
            lrow[r] *= al[r];
          }
#pragma unroll
          for (int n8 = 0; n8 < 8; ++n8)
#pragma unroll
            for (int r = 0; r < 4; ++r) o[n8][r] *= al[r];
        }
#pragma unroll
        for (int r = 0; r < 4; ++r) {
          s0[r] = __builtin_amdgcn_exp2f(s0[r] - mrow[r]);
          s1[r] = __builtin_amdgcn_exp2f(s1[r] - mrow[r]);
        }

        // P (f32, C-layout) -> wave-private LDS -> bf16 A-frag
#pragma unroll
        for (int r = 0; r < 4; ++r) {
          pl[w][4 * g + r][l15] = bfc(s0[r]);
          pl[w][4 * g + r][16 + l15] = bfc(s1[r]);
        }
        bf16x8 pf = *(const bf16x8*)&pl[w][l15][g * 8];  // compiler emits lgkmcnt
        f32x4 z = {};
        f32x4 sm = mfma16(pf, ones, z);  // row-sum of P (replaces shfl tree)
#pragma unroll
        for (int r = 0; r < 4; ++r) lrow[r] += sm[r];
#pragma unroll
        for (int n8 = 0; n8 < 8; ++n8) {
          bf16x8 vf = *(const bf16x8*)&Vs[buf][(g * 128 + n8 * 16 + l15) * 8];
          o[n8] = mfma16(pf, vf, o[n8]);
        }
      }
      __syncthreads();  // all waves done with buf before overwrite
      buf ^= 1;
    }

    float linv[4];
#pragma unroll
    for (int r = 0; r < 4; ++r) linv[r] = 1.0f / lrow[r];
#pragma unroll
    for (int n8 = 0; n8 < 8; ++n8) {
#pragma unroll
      for (int r = 0; r < 4; ++r) {
        const int q = q0 + 4 * g + r;
        O[((size_t)(b * TT + q)) * (NH * HDIM) + h * HDIM + n8 * 16 + l15] =
            f2bf(o[n8][r] * linv[r]);
      }
    }
  }
}

// ---------------------------------------------------------------------- launch
extern "C" void kernel_launch(void* const* d_in, const int* in_sizes, int n_in,
                              void* d_out, int out_size, void* d_ws, size_t ws_size,
                              hipStream_t stream) {
  const float* x  = (const float*)d_in[0];
  const float* Wq = (const float*)d_in[1];
  const float* Wk = (const float*)d_in[2];
  const float* Wv = (const float*)d_in[3];
  const float* Wo = (const float*)d_in[4];
  float* out = (float*)d_out;

  char* ws = (char*)d_ws;
  size_t off = 0;
  unsigned short* xb  = (unsigned short*)(ws + off); off += (size_t)MSZ * DD * 2;   // 32 MiB (reused as O)
  unsigned short* Wtq = (unsigned short*)(ws + off); off += (size_t)NQKV * DD * 2;  // 24 MiB
  unsigned short* Wto = (unsigned short*)(ws + off); off += (size_t)DD * DD * 2;    // 8 MiB
  unsigned short* Qb  = (unsigned short*)(ws + off); off += (size_t)MSZ * DD * 2;   // 32 MiB
  unsigned short* Kb  = (unsigned short*)(ws + off); off += (size_t)MSZ * DD * 2;   // 32 MiB
  unsigned short* Vt  = (unsigned short*)(ws + off); off += (size_t)MSZ * DD * 2;   // 32 MiB
  unsigned short* Ob  = xb;  // x_bf16 dead after QKV GEMM -> reuse for attn out

  cvtx<<<2048, 256, 0, stream>>>(x, xb);
  transW<<<dim3(64, 64, 4), 256, 0, stream>>>(Wq, Wk, Wv, Wo, Wtq, Wto);
  gemm8<0, 24><<<768, 512, 0, stream>>>(xb, Wtq, Qb, Kb, Vt, nullptr);
  attn<<<1024, 256, 0, stream>>>(Qb, Kb, Vt, Ob);
  gemm8<1, 8><<<256, 512, 0, stream>>>(Ob, Wto, nullptr, nullptr, nullptr, out);
}